// Round 4
// baseline (2941.796 us; speedup 1.0000x reference)
//
#include <hip/hip_runtime.h>
#include <math.h>

// Problem constants
#define Nn 50000
#define Ee 800000
#define Bb 256
#define Hh 64
#define TPB 256
#define CHUNK 512
#define NCHK 25000   // ODE node chunk (z buffer = NCHK*128 floats = 12.8MB)

// ---------------- embed: h = x @ W(4x64) + b ----------------
__global__ void k_embed(const float* __restrict__ x, const float* __restrict__ W,
                        const float* __restrict__ b, float* __restrict__ h) {
    int idx = blockIdx.x * blockDim.x + threadIdx.x;
    if (idx >= Nn * Hh) return;
    int n = idx >> 6, j = idx & 63;
    float acc = b[j];
#pragma unroll
    for (int d = 0; d < 4; ++d) acc += x[n * 4 + d] * W[d * Hh + j];
    h[idx] = acc;
}

// ---------------- CSR build ----------------
__global__ void k_hist(const int* __restrict__ dst, int* __restrict__ counts) {
    int e = blockIdx.x * blockDim.x + threadIdx.x;
    if (e < Ee) atomicAdd(&counts[dst[e]], 1);
}

__global__ void k_scan1(const int* __restrict__ counts, int* __restrict__ off,
                        int* __restrict__ chunksum) {
    __shared__ int s[CHUNK];
    int t = threadIdx.x;
    int base = blockIdx.x * CHUNK;
    int v = (base + t < Nn) ? counts[base + t] : 0;
    s[t] = v;
    __syncthreads();
    for (int d = 1; d < CHUNK; d <<= 1) {
        int u = (t >= d) ? s[t - d] : 0;
        __syncthreads();
        s[t] += u;
        __syncthreads();
    }
    if (base + t < Nn) off[base + t + 1] = s[t];
    if (t == CHUNK - 1) chunksum[blockIdx.x] = s[t];
}

__global__ void k_scan2(int* __restrict__ chunksum, int nch) {
    if (blockIdx.x == 0 && threadIdx.x == 0) {
        int run = 0;
        for (int i = 0; i < nch; ++i) { int v = chunksum[i]; chunksum[i] = run; run += v; }
    }
}

__global__ void k_scan3(int* __restrict__ off, const int* __restrict__ chunkoff) {
    int i = blockIdx.x * blockDim.x + threadIdx.x;
    if (i > Nn) return;
    if (i == 0) { off[0] = 0; return; }
    off[i] += chunkoff[(i - 1) >> 9];  // CHUNK=512
}

__global__ void k_copy(const int* __restrict__ off, int* __restrict__ cursor) {
    int n = blockIdx.x * blockDim.x + threadIdx.x;
    if (n < Nn) cursor[n] = off[n];
}

__global__ void k_scatter(const int* __restrict__ src, const int* __restrict__ dst,
                          const float* __restrict__ ea, int* __restrict__ cursor,
                          int* __restrict__ csrc, float* __restrict__ cea) {
    int e = blockIdx.x * blockDim.x + threadIdx.x;
    if (e >= Ee) return;
    int d = dst[e];
    int p = atomicAdd(&cursor[d], 1);
    csrc[p] = src[e];
    cea[p] = ea[e];
}

// fill cdst[p] = n for p in [off[n], off[n+1]) — wave per node, lanes stride the range
__global__ void k_filldst(const int* __restrict__ off, int* __restrict__ cdst) {
    int gid = blockIdx.x * blockDim.x + threadIdx.x;
    int n = gid >> 6, lane = gid & 63;
    if (n >= Nn) return;
    int s = off[n], t = off[n + 1];
    for (int p = s + lane; p < t; p += 64) cdst[p] = n;
}

// ---------------- small transpose: AT[c*R+r] = A[r*C+c] ----------------
__global__ void k_tr(const float* __restrict__ A, float* __restrict__ AT, int R, int C) {
    int idx = blockIdx.x * blockDim.x + threadIdx.x;
    if (idx >= R * C) return;
    int r = idx / C, c = idx - r * C;
    AT[c * R + r] = A[idx];
}

// ---------------- conv linear (float4, transposed weights) ----------------
__global__ void k_lin(const float* __restrict__ h, const float* __restrict__ WlT,
                      const float* __restrict__ bl, const float* __restrict__ WrT,
                      const float* __restrict__ br, float* __restrict__ xl,
                      float* __restrict__ xr) {
    int idx = blockIdx.x * blockDim.x + threadIdx.x;
    if (idx >= Nn * Hh) return;
    int n = idx >> 6, j = idx & 63;
    float al = bl[j], ar = br[j];
    const float4* hr = (const float4*)(h + n * Hh);
    const float4* wl = (const float4*)(WlT + j * Hh);
    const float4* wr = (const float4*)(WrT + j * Hh);
#pragma unroll
    for (int i = 0; i < 16; ++i) {
        float4 hv = hr[i], a = wl[i], b = wr[i];
        al += hv.x * a.x + hv.y * a.y + hv.z * a.z + hv.w * a.w;
        ar += hv.x * b.x + hv.y * b.y + hv.z * b.z + hv.w * b.w;
    }
    xl[idx] = al;
    xr[idx] = ar;
}

// ---------------- edge scores: wave per CSR slot ----------------
__global__ void k_edge(const float* __restrict__ xl, const float* __restrict__ xr,
                       const float* __restrict__ cea, const int* __restrict__ csrc,
                       const int* __restrict__ cdst, const float* __restrict__ We,
                       const float* __restrict__ att, float* __restrict__ ecsr) {
    int gid = blockIdx.x * blockDim.x + threadIdx.x;
    int p = gid >> 6, j = gid & 63;
    if (p >= Ee) return;
    int s = csrc[p], d = cdst[p];
    float m = xl[s * Hh + j] + xr[d * Hh + j] + cea[p] * We[j];
    m = m > 0.f ? m : 0.2f * m;
    float v = m * att[j];
#pragma unroll
    for (int o = 32; o > 0; o >>= 1) v += __shfl_xor(v, o);
    if (j == 0) ecsr[p] = v;
}

// ---------------- fused softmax + aggregate + bias + SiLU: wave per node ----------------
__global__ void k_node(const float* __restrict__ xl, const float* __restrict__ ecsr,
                       const int* __restrict__ csrc, const int* __restrict__ off,
                       const float* __restrict__ bias, float* __restrict__ hout) {
    int gid = blockIdx.x * blockDim.x + threadIdx.x;
    int n = gid >> 6, lane = gid & 63;
    if (n >= Nn) return;
    int s = off[n], t = off[n + 1];
    int deg = t - s;
    float acc = 0.f;
    if (deg > 0) {
        // max
        float m = -1e30f;
        for (int p = s + lane; p < t; p += 64) m = fmaxf(m, ecsr[p]);
#pragma unroll
        for (int o = 32; o > 0; o >>= 1) m = fmaxf(m, __shfl_xor(m, o));
        // sum of exp
        float ssum = 0.f;
        for (int p = s + lane; p < t; p += 64) ssum += expf(ecsr[p] - m);
#pragma unroll
        for (int o = 32; o > 0; o >>= 1) ssum += __shfl_xor(ssum, o);
        float inv = 1.f / ssum;
        // aggregate
        for (int c = s; c < t; c += 64) {
            int cnt = min(64, t - c);
            float le = (c + lane < t) ? ecsr[c + lane] : 0.f;
            int ls = (c + lane < t) ? csrc[c + lane] : 0;
            for (int q = 0; q < cnt; ++q) {
                float a = __shfl(le, q);
                int sr = __shfl(ls, q);
                float w = expf(a - m) * inv;
                acc += w * xl[sr * Hh + lane];
            }
        }
    }
    float o2 = acc + bias[lane];
    hout[n * Hh + lane] = o2 / (1.f + expf(-o2));  // silu
}

// ---------------- RK4 pass A: z[nn,k] = tanh(b1[k] + y . W1T[k,:]) ----------------
template <int STAGE>
__global__ void k_ode_a(const float* __restrict__ h, const float* __restrict__ kprev,
                        const float* __restrict__ W1T, const float* __restrict__ b1,
                        float* __restrict__ z, int n0) {
    int idx = blockIdx.x * blockDim.x + threadIdx.x;
    int nn = idx >> 7, k = idx & 127;
    if (nn >= NCHK) return;
    int n = n0 + nn;
    const float cf = (STAGE == 3) ? 1.0f : 0.5f;
    const float4* hr = (const float4*)(h + n * Hh);
    const float4* kr = (const float4*)(kprev + n * Hh);
    const float4* w = (const float4*)(W1T + k * Hh);
    float acc = b1[k];
#pragma unroll
    for (int i = 0; i < 16; ++i) {
        float4 hv = hr[i];
        float4 wv = w[i];
        if (STAGE != 0) {
            float4 kv = kr[i];
            hv.x += cf * kv.x; hv.y += cf * kv.y; hv.z += cf * kv.z; hv.w += cf * kv.w;
        }
        acc += hv.x * wv.x + hv.y * wv.y + hv.z * wv.z + hv.w * wv.w;
    }
    z[nn * 128 + k] = tanhf(acc);
}

// ---------------- RK4 pass B: out[nn,j] = b2[j] + z . W2T[j,:], + stage epilogue ----------------
template <int STAGE>
__global__ void k_ode_b(float* __restrict__ h, const float* __restrict__ z,
                        const float* __restrict__ W2T, const float* __restrict__ b2,
                        float* __restrict__ kout, float* __restrict__ ksum, int n0) {
    int idx = blockIdx.x * blockDim.x + threadIdx.x;
    int nn = idx >> 6, j = idx & 63;
    if (nn >= NCHK) return;
    int n = n0 + nn;
    const float4* zr = (const float4*)(z + nn * 128);
    const float4* w = (const float4*)(W2T + j * 128);
    float acc = b2[j];
#pragma unroll
    for (int k = 0; k < 32; ++k) {
        float4 zv = zr[k], wv = w[k];
        acc += zv.x * wv.x + zv.y * wv.y + zv.z * wv.z + zv.w * wv.w;
    }
    int gi = n * Hh + j;
    if (STAGE == 0) {
        kout[gi] = acc;
        ksum[gi] = acc;
    } else if (STAGE == 3) {
        h[gi] = h[gi] + (ksum[gi] + acc) * (1.f / 6.f);
    } else {
        kout[gi] = acc;
        ksum[gi] += 2.f * acc;
    }
}

// ---------------- pooling ----------------
__global__ void k_binit(int* __restrict__ gs, int* __restrict__ ge) {
    int b = threadIdx.x;
    if (b < Bb) { gs[b] = 0; ge[b] = 0; }
}

__global__ void k_bounds(const int* __restrict__ batch, int* __restrict__ gs,
                         int* __restrict__ ge) {
    int n = blockIdx.x * blockDim.x + threadIdx.x;
    if (n >= Nn) return;
    int b = batch[n];
    if (n == 0 || batch[n - 1] != b) gs[b] = n;
    if (n == Nn - 1 || batch[n + 1] != b) ge[b] = n + 1;
}

// block per graph, 4 waves, LDS combine (deterministic)
__global__ void k_pool(const float* __restrict__ h, const int* __restrict__ gs,
                       const int* __restrict__ ge, float* __restrict__ g) {
    int b = blockIdx.x;
    int s = gs[b], e = ge[b];
    int w = threadIdx.x >> 6, lane = threadIdx.x & 63;
    float sum = 0.f, mx = -1e30f;
    for (int n = s + w; n < e; n += 4) {
        float v = h[n * Hh + lane];
        sum += v;
        mx = fmaxf(mx, v);
    }
    __shared__ float ssum[4][64], smx[4][64];
    ssum[w][lane] = sum;
    smx[w][lane] = mx;
    __syncthreads();
    if (threadIdx.x < 64) {
        int j = threadIdx.x;
        float su = ssum[0][j] + ssum[1][j] + ssum[2][j] + ssum[3][j];
        float m2 = fmaxf(fmaxf(smx[0][j], smx[1][j]), fmaxf(smx[2][j], smx[3][j]));
        int cnt = e - s;
        g[b * 2 * Hh + j] = (cnt > 0) ? su / (float)cnt : 0.f;
        g[b * 2 * Hh + Hh + j] = (cnt > 0) ? m2 : 0.f;
    }
}

// ---------------- predictor head: wave per graph ----------------
__global__ void k_pred(const float* __restrict__ g, const float* __restrict__ W1,
                       const float* __restrict__ b1, const float* __restrict__ W2,
                       const float* __restrict__ b2, float* __restrict__ out) {
    int gid = blockIdx.x * blockDim.x + threadIdx.x;
    int b = gid >> 6, lane = gid & 63;
    if (b >= Bb) return;
    int hh = lane & 31, half = lane >> 5;
    const float* gr = g + b * 2 * Hh + half * Hh;
    float a = 0.f;
#pragma unroll 8
    for (int i = 0; i < Hh; ++i) a += gr[i] * W1[(half * Hh + i) * 32 + hh];
    a += __shfl_xor(a, 32);
    a += b1[hh];
    float sl = a / (1.f + expf(-a));
    float partial = (half == 0) ? sl * W2[hh] : 0.f;
#pragma unroll
    for (int o = 32; o > 0; o >>= 1) partial += __shfl_xor(partial, o);
    if (lane == 0) out[b] = partial + b2[0];
}

extern "C" void kernel_launch(void* const* d_in, const int* in_sizes, int n_in,
                              void* d_out, int out_size, void* d_ws, size_t ws_size,
                              hipStream_t stream) {
    const float* x     = (const float*)d_in[0];
    const int*   ei    = (const int*)d_in[1];
    const float* ea    = (const float*)d_in[2];
    const int*   batch = (const int*)d_in[3];
    const float* embW  = (const float*)d_in[4];
    const float* embB  = (const float*)d_in[5];
    const float* c1Wl = (const float*)d_in[6];  const float* c1bl = (const float*)d_in[7];
    const float* c1Wr = (const float*)d_in[8];  const float* c1br = (const float*)d_in[9];
    const float* c1We = (const float*)d_in[10]; const float* c1att = (const float*)d_in[11];
    const float* c1bias = (const float*)d_in[12];
    const float* c2Wl = (const float*)d_in[13]; const float* c2bl = (const float*)d_in[14];
    const float* c2Wr = (const float*)d_in[15]; const float* c2br = (const float*)d_in[16];
    const float* c2We = (const float*)d_in[17]; const float* c2att = (const float*)d_in[18];
    const float* c2bias = (const float*)d_in[19];
    const float* oW1 = (const float*)d_in[20]; const float* ob1 = (const float*)d_in[21];
    const float* oW2 = (const float*)d_in[22]; const float* ob2 = (const float*)d_in[23];
    const float* pW1 = (const float*)d_in[24]; const float* pb1 = (const float*)d_in[25];
    const float* pW2 = (const float*)d_in[26]; const float* pb2 = (const float*)d_in[27];
    float* out = (float*)d_out;

    // workspace layout (floats)
    float* fws = (float*)d_ws;
    size_t NH = (size_t)Nn * Hh;           // 3.2M
    float* h    = fws;
    float* xl   = fws + NH;                // RK4: kA
    float* xr   = fws + 2 * NH;            // RK4: kB
    float* ksum = fws + 3 * NH;
    float* zreg = fws + 4 * NH;            // 3.2M floats shared: CSR edge arrays / ODE z
    float* ecsr = zreg;                    // [Ee]
    float* cea  = zreg + Ee;               // [Ee]
    int*   csrc = (int*)(zreg + 2 * (size_t)Ee);  // [Ee]
    int*   cdst = (int*)(zreg + 3 * (size_t)Ee);  // [Ee]  (holds dst CSR copy)
    float* z    = zreg;                    // aliases CSR arrays after convs are done
    float* g    = fws + 5 * NH;            // [Bb*128]
    float* W1T  = g + (size_t)Bb * 128;    // [128*64]
    float* W2T  = W1T + 128 * 64;          // [64*128]
    float* WlT  = W2T + 64 * 128;          // [64*64]
    float* WrT  = WlT + 64 * 64;           // [64*64]
    int* iws = (int*)(WrT + 64 * 64);
    int* counts = iws;                     // [Nn]
    int* off    = counts + Nn;             // [Nn+1]
    int* cursor = off + Nn + 1;            // [Nn]
    int* chk    = cursor + Nn;             // [128]
    int* gs     = chk + 128;               // [Bb]
    int* ge     = gs + Bb;                 // [Bb]

    const int* src = ei;
    const int* dst = ei + Ee;

    hipMemsetAsync(counts, 0, Nn * sizeof(int), stream);
    k_embed<<<(Nn * Hh + TPB - 1) / TPB, TPB, 0, stream>>>(x, embW, embB, h);
    k_hist<<<(Ee + TPB - 1) / TPB, TPB, 0, stream>>>(dst, counts);
    k_scan1<<<(Nn + CHUNK - 1) / CHUNK, CHUNK, 0, stream>>>(counts, off, chk);
    k_scan2<<<1, 64, 0, stream>>>(chk, (Nn + CHUNK - 1) / CHUNK);
    k_scan3<<<(Nn + 1 + TPB - 1) / TPB, TPB, 0, stream>>>(off, chk);
    k_copy<<<(Nn + TPB - 1) / TPB, TPB, 0, stream>>>(off, cursor);
    k_scatter<<<(Ee + TPB - 1) / TPB, TPB, 0, stream>>>(src, dst, ea, cursor, csrc, cea);
    k_filldst<<<(Nn * Hh + TPB - 1) / TPB, TPB, 0, stream>>>(off, cdst);

    // conv1
    k_tr<<<(64 * 64 + TPB - 1) / TPB, TPB, 0, stream>>>(c1Wl, WlT, 64, 64);
    k_tr<<<(64 * 64 + TPB - 1) / TPB, TPB, 0, stream>>>(c1Wr, WrT, 64, 64);
    k_lin<<<(Nn * Hh + TPB - 1) / TPB, TPB, 0, stream>>>(h, WlT, c1bl, WrT, c1br, xl, xr);
    k_edge<<<((size_t)Ee * 64 + TPB - 1) / TPB, TPB, 0, stream>>>(xl, xr, cea, csrc, cdst, c1We, c1att, ecsr);
    k_node<<<(Nn * 64 + TPB - 1) / TPB, TPB, 0, stream>>>(xl, ecsr, csrc, off, c1bias, h);

    // conv2
    k_tr<<<(64 * 64 + TPB - 1) / TPB, TPB, 0, stream>>>(c2Wl, WlT, 64, 64);
    k_tr<<<(64 * 64 + TPB - 1) / TPB, TPB, 0, stream>>>(c2Wr, WrT, 64, 64);
    k_lin<<<(Nn * Hh + TPB - 1) / TPB, TPB, 0, stream>>>(h, WlT, c2bl, WrT, c2br, xl, xr);
    k_edge<<<((size_t)Ee * 64 + TPB - 1) / TPB, TPB, 0, stream>>>(xl, xr, cea, csrc, cdst, c2We, c2att, ecsr);
    k_node<<<(Nn * 64 + TPB - 1) / TPB, TPB, 0, stream>>>(xl, ecsr, csrc, off, c2bias, h);

    // RK4: z aliases the edge arrays (dead from here on). kA=xl, kB=xr.
    k_tr<<<(64 * 128 + TPB - 1) / TPB, TPB, 0, stream>>>(oW1, W1T, 64, 128);
    k_tr<<<(128 * 64 + TPB - 1) / TPB, TPB, 0, stream>>>(oW2, W2T, 128, 64);
    int gA = (NCHK * 128 + TPB - 1) / TPB, gB = (NCHK * 64 + TPB - 1) / TPB;
    for (int c = 0; c < 2; ++c) {
        int n0 = c * NCHK;
        k_ode_a<0><<<gA, TPB, 0, stream>>>(h, h, W1T, ob1, z, n0);
        k_ode_b<0><<<gB, TPB, 0, stream>>>(h, z, W2T, ob2, xl, ksum, n0);
    }
    for (int c = 0; c < 2; ++c) {
        int n0 = c * NCHK;
        k_ode_a<1><<<gA, TPB, 0, stream>>>(h, xl, W1T, ob1, z, n0);
        k_ode_b<1><<<gB, TPB, 0, stream>>>(h, z, W2T, ob2, xr, ksum, n0);
    }
    for (int c = 0; c < 2; ++c) {
        int n0 = c * NCHK;
        k_ode_a<2><<<gA, TPB, 0, stream>>>(h, xr, W1T, ob1, z, n0);
        k_ode_b<2><<<gB, TPB, 0, stream>>>(h, z, W2T, ob2, xl, ksum, n0);
    }
    for (int c = 0; c < 2; ++c) {
        int n0 = c * NCHK;
        k_ode_a<3><<<gA, TPB, 0, stream>>>(h, xl, W1T, ob1, z, n0);
        k_ode_b<3><<<gB, TPB, 0, stream>>>(h, z, W2T, ob2, xr, ksum, n0);
    }

    // pooling + head
    k_binit<<<1, Bb, 0, stream>>>(gs, ge);
    k_bounds<<<(Nn + TPB - 1) / TPB, TPB, 0, stream>>>(batch, gs, ge);
    k_pool<<<Bb, 256, 0, stream>>>(h, gs, ge, g);
    k_pred<<<(Bb * 64 + TPB - 1) / TPB, TPB, 0, stream>>>(g, pW1, pb1, pW2, pb2, out);
}

// Round 7
// 1180.027 us; speedup vs baseline: 2.4930x; 2.4930x over previous
//
#include <hip/hip_runtime.h>
#include <math.h>

// Problem constants
#define Nn 50000
#define Ee 800000
#define Bb 256
#define Hh 64
#define TPB 256
#define CHUNK 512

// ---------------- embed: h = x @ W(4x64) + b ----------------
__global__ void k_embed(const float* __restrict__ x, const float* __restrict__ W,
                        const float* __restrict__ b, float* __restrict__ h) {
    int idx = blockIdx.x * blockDim.x + threadIdx.x;
    if (idx >= Nn * Hh) return;
    int n = idx >> 6, j = idx & 63;
    float acc = b[j];
#pragma unroll
    for (int d = 0; d < 4; ++d) acc += x[n * 4 + d] * W[d * Hh + j];
    h[idx] = acc;
}

// ---------------- CSR build ----------------
__global__ void k_hist(const int* __restrict__ dst, int* __restrict__ counts) {
    int e = blockIdx.x * blockDim.x + threadIdx.x;
    if (e < Ee) atomicAdd(&counts[dst[e]], 1);
}

__global__ void k_scan1(const int* __restrict__ counts, int* __restrict__ off,
                        int* __restrict__ chunksum) {
    __shared__ int s[CHUNK];
    int t = threadIdx.x;
    int base = blockIdx.x * CHUNK;
    int v = (base + t < Nn) ? counts[base + t] : 0;
    s[t] = v;
    __syncthreads();
    for (int d = 1; d < CHUNK; d <<= 1) {
        int u = (t >= d) ? s[t - d] : 0;
        __syncthreads();
        s[t] += u;
        __syncthreads();
    }
    if (base + t < Nn) off[base + t + 1] = s[t];
    if (t == CHUNK - 1) chunksum[blockIdx.x] = s[t];
}

__global__ void k_scan2(int* __restrict__ chunksum, int nch) {
    if (blockIdx.x == 0 && threadIdx.x == 0) {
        int run = 0;
        for (int i = 0; i < nch; ++i) { int v = chunksum[i]; chunksum[i] = run; run += v; }
    }
}

__global__ void k_scan3(int* __restrict__ off, const int* __restrict__ chunkoff) {
    int i = blockIdx.x * blockDim.x + threadIdx.x;
    if (i > Nn) return;
    if (i == 0) { off[0] = 0; return; }
    off[i] += chunkoff[(i - 1) >> 9];  // CHUNK=512
}

__global__ void k_copy(const int* __restrict__ off, int* __restrict__ cursor) {
    int n = blockIdx.x * blockDim.x + threadIdx.x;
    if (n < Nn) cursor[n] = off[n];
}

__global__ void k_scatter(const int* __restrict__ src, const int* __restrict__ dst,
                          const float* __restrict__ ea, int* __restrict__ cursor,
                          int* __restrict__ csrc, float* __restrict__ cea) {
    int e = blockIdx.x * blockDim.x + threadIdx.x;
    if (e >= Ee) return;
    int d = dst[e];
    int p = atomicAdd(&cursor[d], 1);
    csrc[p] = src[e];
    cea[p] = ea[e];
}

// fill cdst[p] = n for p in [off[n], off[n+1)) — wave per node
__global__ void k_filldst(const int* __restrict__ off, int* __restrict__ cdst) {
    int gid = blockIdx.x * blockDim.x + threadIdx.x;
    int n = gid >> 6, lane = gid & 63;
    if (n >= Nn) return;
    int s = off[n], t = off[n + 1];
    for (int p = s + lane; p < t; p += 64) cdst[p] = n;
}

// ---------------- conv linear: lane = output col (coalesced weights), 4 nodes/thread ----
// xl = h@Wl+bl, xr = h@Wr+br.  W stored [in=64][out=64]: W[i*64+lane] coalesced.
__global__ __launch_bounds__(256) void k_lin(const float* __restrict__ h,
                      const float* __restrict__ Wl, const float* __restrict__ bl,
                      const float* __restrict__ Wr, const float* __restrict__ br,
                      float* __restrict__ xl, float* __restrict__ xr) {
    int lane = threadIdx.x & 63, w = threadIdx.x >> 6;
    int n0 = blockIdx.x * 16 + w * 4;      // 4 nodes per wave, 16 per block
    float al[4], ar[4];
#pragma unroll
    for (int q = 0; q < 4; ++q) { al[q] = bl[lane]; ar[q] = br[lane]; }
    for (int i4 = 0; i4 < 16; ++i4) {
        float4 hv[4];
#pragma unroll
        for (int q = 0; q < 4; ++q)
            hv[q] = *(const float4*)(h + (n0 + q) * 64 + i4 * 4);   // wave-uniform broadcast
#pragma unroll
        for (int u = 0; u < 4; ++u) {
            int i = i4 * 4 + u;
            float wlv = Wl[i * 64 + lane];   // coalesced across lanes
            float wrv = Wr[i * 64 + lane];
#pragma unroll
            for (int q = 0; q < 4; ++q) {
                float hq = ((const float*)&hv[q])[u];
                al[q] += hq * wlv;
                ar[q] += hq * wrv;
            }
        }
    }
#pragma unroll
    for (int q = 0; q < 4; ++q) {
        xl[(n0 + q) * 64 + lane] = al[q];
        xr[(n0 + q) * 64 + lane] = ar[q];
    }
}

// ---------------- edge scores: wave per CSR slot ----------------
__global__ void k_edge(const float* __restrict__ xl, const float* __restrict__ xr,
                       const float* __restrict__ cea, const int* __restrict__ csrc,
                       const int* __restrict__ cdst, const float* __restrict__ We,
                       const float* __restrict__ att, float* __restrict__ ecsr) {
    int gid = blockIdx.x * blockDim.x + threadIdx.x;
    int p = gid >> 6, j = gid & 63;
    if (p >= Ee) return;
    int s = csrc[p], d = cdst[p];
    float m = xl[s * Hh + j] + xr[d * Hh + j] + cea[p] * We[j];
    m = m > 0.f ? m : 0.2f * m;
    float v = m * att[j];
#pragma unroll
    for (int o = 32; o > 0; o >>= 1) v += __shfl_xor(v, o);
    if (j == 0) ecsr[p] = v;
}

// ---------------- fused softmax + aggregate + bias + SiLU: wave per node ----------------
__global__ void k_node(const float* __restrict__ xl, const float* __restrict__ ecsr,
                       const int* __restrict__ csrc, const int* __restrict__ off,
                       const float* __restrict__ bias, float* __restrict__ hout) {
    int gid = blockIdx.x * blockDim.x + threadIdx.x;
    int n = gid >> 6, lane = gid & 63;
    if (n >= Nn) return;
    int s = off[n], t = off[n + 1];
    int deg = t - s;
    float acc = 0.f;
    if (deg > 0) {
        float m = -1e30f;
        for (int p = s + lane; p < t; p += 64) m = fmaxf(m, ecsr[p]);
#pragma unroll
        for (int o = 32; o > 0; o >>= 1) m = fmaxf(m, __shfl_xor(m, o));
        float ssum = 0.f;
        for (int p = s + lane; p < t; p += 64) ssum += expf(ecsr[p] - m);
#pragma unroll
        for (int o = 32; o > 0; o >>= 1) ssum += __shfl_xor(ssum, o);
        float inv = 1.f / ssum;
        for (int c = s; c < t; c += 64) {
            int cnt = min(64, t - c);
            float le = (c + lane < t) ? ecsr[c + lane] : 0.f;
            int ls = (c + lane < t) ? csrc[c + lane] : 0;
            for (int q = 0; q < cnt; ++q) {
                float a = __shfl(le, q);
                int sr = __shfl(ls, q);
                float wgt = expf(a - m) * inv;
                acc += wgt * xl[sr * Hh + lane];
            }
        }
    }
    float o2 = acc + bias[lane];
    hout[n * Hh + lane] = o2 / (1.f + expf(-o2));  // silu
}

// ---------------- RK4 stage, fused two-layer MLP via LDS z-tile ----------------
// block = 256 threads = 16 nodes. phase1: z[16][128] = tanh(y@W1+b1) (8 nodes/thread),
// phase2: out[16][64] = z@W2+b2 (4 nodes/thread) + stage epilogue.
// W1 [64][128], W2 [128][64] used in original layout (coalesced across lanes).
template <int STAGE>
__global__ __launch_bounds__(256) void k_ode(float* __restrict__ h,
        const float* __restrict__ kprev,
        const float* __restrict__ W1, const float* __restrict__ b1,
        const float* __restrict__ W2, const float* __restrict__ b2,
        float* __restrict__ kout, float* __restrict__ ksum) {
    __shared__ float zt[16][128];
    int t = threadIdx.x;
    int nb = blockIdx.x * 16;
    {   // phase 1
        int k = t & 127;
        int g = t >> 7;  // node subgroup: 8 nodes each
        const float cf = (STAGE == 3) ? 1.0f : 0.5f;
        float acc[8];
#pragma unroll
        for (int q = 0; q < 8; ++q) acc[q] = b1[k];
        for (int i4 = 0; i4 < 16; ++i4) {
            float4 yv[8];
#pragma unroll
            for (int q = 0; q < 8; ++q) {
                int n = nb + g * 8 + q;
                float4 hv = *(const float4*)(h + n * 64 + i4 * 4);      // broadcast
                if (STAGE != 0) {
                    float4 kv = *(const float4*)(kprev + n * 64 + i4 * 4);
                    hv.x += cf * kv.x; hv.y += cf * kv.y;
                    hv.z += cf * kv.z; hv.w += cf * kv.w;
                }
                yv[q] = hv;
            }
#pragma unroll
            for (int u = 0; u < 4; ++u) {
                float wv = W1[(i4 * 4 + u) * 128 + k];                  // coalesced
#pragma unroll
                for (int q = 0; q < 8; ++q)
                    acc[q] += ((const float*)&yv[q])[u] * wv;
            }
        }
#pragma unroll
        for (int q = 0; q < 8; ++q) zt[g * 8 + q][k] = tanhf(acc[q]);
    }
    __syncthreads();
    {   // phase 2
        int j = t & 63;
        int w = t >> 6;  // 4 nodes each
        float acc[4];
#pragma unroll
        for (int q = 0; q < 4; ++q) acc[q] = b2[j];
        for (int k4 = 0; k4 < 32; ++k4) {
            float4 zv[4];
#pragma unroll
            for (int q = 0; q < 4; ++q)
                zv[q] = *(const float4*)&zt[w * 4 + q][k4 * 4];          // LDS broadcast
#pragma unroll
            for (int u = 0; u < 4; ++u) {
                float wv = W2[(k4 * 4 + u) * 64 + j];                    // coalesced
#pragma unroll
                for (int q = 0; q < 4; ++q)
                    acc[q] += ((const float*)&zv[q])[u] * wv;
            }
        }
#pragma unroll
        for (int q = 0; q < 4; ++q) {
            int gi = (nb + w * 4 + q) * 64 + j;
            if (STAGE == 0)      { kout[gi] = acc[q]; ksum[gi] = acc[q]; }
            else if (STAGE == 3) { h[gi] = h[gi] + (ksum[gi] + acc[q]) * (1.f / 6.f); }
            else                 { kout[gi] = acc[q]; ksum[gi] += 2.f * acc[q]; }
        }
    }
}

// ---------------- pooling ----------------
__global__ void k_binit(int* __restrict__ gs, int* __restrict__ ge) {
    int b = threadIdx.x;
    if (b < Bb) { gs[b] = 0; ge[b] = 0; }
}

__global__ void k_bounds(const int* __restrict__ batch, int* __restrict__ gs,
                         int* __restrict__ ge) {
    int n = blockIdx.x * blockDim.x + threadIdx.x;
    if (n >= Nn) return;
    int b = batch[n];
    if (n == 0 || batch[n - 1] != b) gs[b] = n;
    if (n == Nn - 1 || batch[n + 1] != b) ge[b] = n + 1;
}

// block per graph, 4 waves, LDS combine (deterministic)
__global__ void k_pool(const float* __restrict__ h, const int* __restrict__ gs,
                       const int* __restrict__ ge, float* __restrict__ g) {
    int b = blockIdx.x;
    int s = gs[b], e = ge[b];
    int w = threadIdx.x >> 6, lane = threadIdx.x & 63;
    float sum = 0.f, mx = -1e30f;
    for (int n = s + w; n < e; n += 4) {
        float v = h[n * Hh + lane];
        sum += v;
        mx = fmaxf(mx, v);
    }
    __shared__ float ssum[4][64], smx[4][64];
    ssum[w][lane] = sum;
    smx[w][lane] = mx;
    __syncthreads();
    if (threadIdx.x < 64) {
        int j = threadIdx.x;
        float su = ssum[0][j] + ssum[1][j] + ssum[2][j] + ssum[3][j];
        float m2 = fmaxf(fmaxf(smx[0][j], smx[1][j]), fmaxf(smx[2][j], smx[3][j]));
        int cnt = e - s;
        g[b * 2 * Hh + j] = (cnt > 0) ? su / (float)cnt : 0.f;
        g[b * 2 * Hh + Hh + j] = (cnt > 0) ? m2 : 0.f;
    }
}

// ---------------- predictor head: wave per graph ----------------
__global__ void k_pred(const float* __restrict__ g, const float* __restrict__ W1,
                       const float* __restrict__ b1, const float* __restrict__ W2,
                       const float* __restrict__ b2, float* __restrict__ out) {
    int gid = blockIdx.x * blockDim.x + threadIdx.x;
    int b = gid >> 6, lane = gid & 63;
    if (b >= Bb) return;
    int hh = lane & 31, half = lane >> 5;
    const float* gr = g + b * 2 * Hh + half * Hh;
    float a = 0.f;
#pragma unroll 8
    for (int i = 0; i < Hh; ++i) a += gr[i] * W1[(half * Hh + i) * 32 + hh];
    a += __shfl_xor(a, 32);
    a += b1[hh];
    float sl = a / (1.f + expf(-a));
    float partial = (half == 0) ? sl * W2[hh] : 0.f;
#pragma unroll
    for (int o = 32; o > 0; o >>= 1) partial += __shfl_xor(partial, o);
    if (lane == 0) out[b] = partial + b2[0];
}

extern "C" void kernel_launch(void* const* d_in, const int* in_sizes, int n_in,
                              void* d_out, int out_size, void* d_ws, size_t ws_size,
                              hipStream_t stream) {
    const float* x     = (const float*)d_in[0];
    const int*   ei    = (const int*)d_in[1];
    const float* ea    = (const float*)d_in[2];
    const int*   batch = (const int*)d_in[3];
    const float* embW  = (const float*)d_in[4];
    const float* embB  = (const float*)d_in[5];
    const float* c1Wl = (const float*)d_in[6];  const float* c1bl = (const float*)d_in[7];
    const float* c1Wr = (const float*)d_in[8];  const float* c1br = (const float*)d_in[9];
    const float* c1We = (const float*)d_in[10]; const float* c1att = (const float*)d_in[11];
    const float* c1bias = (const float*)d_in[12];
    const float* c2Wl = (const float*)d_in[13]; const float* c2bl = (const float*)d_in[14];
    const float* c2Wr = (const float*)d_in[15]; const float* c2br = (const float*)d_in[16];
    const float* c2We = (const float*)d_in[17]; const float* c2att = (const float*)d_in[18];
    const float* c2bias = (const float*)d_in[19];
    const float* oW1 = (const float*)d_in[20]; const float* ob1 = (const float*)d_in[21];
    const float* oW2 = (const float*)d_in[22]; const float* ob2 = (const float*)d_in[23];
    const float* pW1 = (const float*)d_in[24]; const float* pb1 = (const float*)d_in[25];
    const float* pW2 = (const float*)d_in[26]; const float* pb2 = (const float*)d_in[27];
    float* out = (float*)d_out;

    // workspace layout (floats)
    float* fws = (float*)d_ws;
    size_t NH = (size_t)Nn * Hh;           // 3.2M
    float* h    = fws;
    float* xl   = fws + NH;                // RK4: kA
    float* xr   = fws + 2 * NH;            // RK4: kB
    float* ksum = fws + 3 * NH;
    float* zreg = fws + 4 * NH;            // CSR edge arrays
    float* ecsr = zreg;                    // [Ee]
    float* cea  = zreg + Ee;               // [Ee]
    int*   csrc = (int*)(zreg + 2 * (size_t)Ee);  // [Ee]
    int*   cdst = (int*)(zreg + 3 * (size_t)Ee);  // [Ee]
    float* g    = fws + 5 * NH;            // [Bb*128]
    int* iws = (int*)(g + (size_t)Bb * 128);
    int* counts = iws;                     // [Nn]
    int* off    = counts + Nn;             // [Nn+1]
    int* cursor = off + Nn + 1;            // [Nn]
    int* chk    = cursor + Nn;             // [128]
    int* gs     = chk + 128;               // [Bb]
    int* ge     = gs + Bb;                 // [Bb]

    const int* src = ei;
    const int* dst = ei + Ee;

    hipMemsetAsync(counts, 0, Nn * sizeof(int), stream);
    k_embed<<<(Nn * Hh + TPB - 1) / TPB, TPB, 0, stream>>>(x, embW, embB, h);
    k_hist<<<(Ee + TPB - 1) / TPB, TPB, 0, stream>>>(dst, counts);
    k_scan1<<<(Nn + CHUNK - 1) / CHUNK, CHUNK, 0, stream>>>(counts, off, chk);
    k_scan2<<<1, 64, 0, stream>>>(chk, (Nn + CHUNK - 1) / CHUNK);
    k_scan3<<<(Nn + 1 + TPB - 1) / TPB, TPB, 0, stream>>>(off, chk);
    k_copy<<<(Nn + TPB - 1) / TPB, TPB, 0, stream>>>(off, cursor);
    k_scatter<<<(Ee + TPB - 1) / TPB, TPB, 0, stream>>>(src, dst, ea, cursor, csrc, cea);
    k_filldst<<<(Nn * 64 + TPB - 1) / TPB, TPB, 0, stream>>>(off, cdst);

    // conv1  (N/16 = 3125 blocks for k_lin)
    k_lin<<<Nn / 16, TPB, 0, stream>>>(h, c1Wl, c1bl, c1Wr, c1br, xl, xr);
    k_edge<<<((size_t)Ee * 64 + TPB - 1) / TPB, TPB, 0, stream>>>(xl, xr, cea, csrc, cdst, c1We, c1att, ecsr);
    k_node<<<(Nn * 64 + TPB - 1) / TPB, TPB, 0, stream>>>(xl, ecsr, csrc, off, c1bias, h);

    // conv2
    k_lin<<<Nn / 16, TPB, 0, stream>>>(h, c2Wl, c2bl, c2Wr, c2br, xl, xr);
    k_edge<<<((size_t)Ee * 64 + TPB - 1) / TPB, TPB, 0, stream>>>(xl, xr, cea, csrc, cdst, c2We, c2att, ecsr);
    k_node<<<(Nn * 64 + TPB - 1) / TPB, TPB, 0, stream>>>(xl, ecsr, csrc, off, c2bias, h);

    // RK4: fused per-stage kernels. k1=xl, k2=xr, k3=xl, k4 consumed in-place.
    int gOde = Nn / 16;  // 3125 blocks
    k_ode<0><<<gOde, TPB, 0, stream>>>(h, h,  oW1, ob1, oW2, ob2, xl, ksum);
    k_ode<1><<<gOde, TPB, 0, stream>>>(h, xl, oW1, ob1, oW2, ob2, xr, ksum);
    k_ode<2><<<gOde, TPB, 0, stream>>>(h, xr, oW1, ob1, oW2, ob2, xl, ksum);
    k_ode<3><<<gOde, TPB, 0, stream>>>(h, xl, oW1, ob1, oW2, ob2, xr, ksum);

    // pooling + head
    k_binit<<<1, Bb, 0, stream>>>(gs, ge);
    k_bounds<<<(Nn + TPB - 1) / TPB, TPB, 0, stream>>>(batch, gs, ge);
    k_pool<<<Bb, 256, 0, stream>>>(h, gs, ge, g);
    k_pred<<<(Bb * 64 + TPB - 1) / TPB, TPB, 0, stream>>>(g, pW1, pb1, pW2, pb2, out);
}

// Round 9
// 738.110 us; speedup vs baseline: 3.9856x; 1.5987x over previous
//
#include <hip/hip_runtime.h>
#include <math.h>

// Problem constants
#define Nn 50000
#define Ee 800000
#define Bb 256
#define Hh 64
#define TPB 256
#define CHUNK 512

// ---------------- embed: h = x @ W(4x64) + b ----------------
__global__ void k_embed(const float* __restrict__ x, const float* __restrict__ W,
                        const float* __restrict__ b, float* __restrict__ h) {
    int idx = blockIdx.x * blockDim.x + threadIdx.x;
    if (idx >= Nn * Hh) return;
    int n = idx >> 6, j = idx & 63;
    float acc = b[j];
#pragma unroll
    for (int d = 0; d < 4; ++d) acc += x[n * 4 + d] * W[d * Hh + j];
    h[idx] = acc;
}

// ---------------- CSR build ----------------
__global__ void k_hist(const int* __restrict__ dst, int* __restrict__ counts) {
    int e = blockIdx.x * blockDim.x + threadIdx.x;
    if (e < Ee) atomicAdd(&counts[dst[e]], 1);
}

__global__ void k_scan1(const int* __restrict__ counts, int* __restrict__ off,
                        int* __restrict__ chunksum) {
    __shared__ int s[CHUNK];
    int t = threadIdx.x;
    int base = blockIdx.x * CHUNK;
    int v = (base + t < Nn) ? counts[base + t] : 0;
    s[t] = v;
    __syncthreads();
    for (int d = 1; d < CHUNK; d <<= 1) {
        int u = (t >= d) ? s[t - d] : 0;
        __syncthreads();
        s[t] += u;
        __syncthreads();
    }
    if (base + t < Nn) off[base + t + 1] = s[t];
    if (t == CHUNK - 1) chunksum[blockIdx.x] = s[t];
}

__global__ void k_scan2(int* __restrict__ chunksum, int nch) {
    if (blockIdx.x == 0 && threadIdx.x == 0) {
        int run = 0;
        for (int i = 0; i < nch; ++i) { int v = chunksum[i]; chunksum[i] = run; run += v; }
    }
}

__global__ void k_scan3(int* __restrict__ off, const int* __restrict__ chunkoff) {
    int i = blockIdx.x * blockDim.x + threadIdx.x;
    if (i > Nn) return;
    if (i == 0) { off[0] = 0; return; }
    off[i] += chunkoff[(i - 1) >> 9];  // CHUNK=512
}

__global__ void k_copy(const int* __restrict__ off, int* __restrict__ cursor) {
    int n = blockIdx.x * blockDim.x + threadIdx.x;
    if (n < Nn) cursor[n] = off[n];
}

__global__ void k_scatter(const int* __restrict__ src, const int* __restrict__ dst,
                          const float* __restrict__ ea, int* __restrict__ cursor,
                          int* __restrict__ csrc, float* __restrict__ cea) {
    int e = blockIdx.x * blockDim.x + threadIdx.x;
    if (e >= Ee) return;
    int d = dst[e];
    int p = atomicAdd(&cursor[d], 1);
    csrc[p] = src[e];
    cea[p] = ea[e];
}

// ---------------- conv linear: lane = output col (coalesced weights), 4 nodes/thread ----
__global__ __launch_bounds__(256) void k_lin(const float* __restrict__ h,
                      const float* __restrict__ Wl, const float* __restrict__ bl,
                      const float* __restrict__ Wr, const float* __restrict__ br,
                      float* __restrict__ xl, float* __restrict__ xr) {
    int lane = threadIdx.x & 63, w = threadIdx.x >> 6;
    int n0 = blockIdx.x * 16 + w * 4;      // 4 nodes per wave, 16 per block
    float al[4], ar[4];
#pragma unroll
    for (int q = 0; q < 4; ++q) { al[q] = bl[lane]; ar[q] = br[lane]; }
    for (int i4 = 0; i4 < 16; ++i4) {
        float4 hv[4];
#pragma unroll
        for (int q = 0; q < 4; ++q)
            hv[q] = *(const float4*)(h + (n0 + q) * 64 + i4 * 4);   // wave-uniform broadcast
#pragma unroll
        for (int u = 0; u < 4; ++u) {
            int i = i4 * 4 + u;
            float wlv = Wl[i * 64 + lane];   // coalesced across lanes
            float wrv = Wr[i * 64 + lane];
#pragma unroll
            for (int q = 0; q < 4; ++q) {
                float hq = ((const float*)&hv[q])[u];
                al[q] += hq * wlv;
                ar[q] += hq * wrv;
            }
        }
    }
#pragma unroll
    for (int q = 0; q < 4; ++q) {
        xl[(n0 + q) * 64 + lane] = al[q];
        xr[(n0 + q) * 64 + lane] = ar[q];
    }
}

// ---------------- fused GATv2 conv: scores + softmax + aggregate + SiLU, wave/node ----
// Per 64-edge chunk: pass A gathers xl[src] rows once, computes e_p into lane slot;
// online-softmax rescale; pass B re-gathers (L1-hot) and accumulates alpha*xl[src].
__global__ void k_conv(const float* __restrict__ xl, const float* __restrict__ xr,
                       const float* __restrict__ cea, const int* __restrict__ csrc,
                       const int* __restrict__ off, const float* __restrict__ We,
                       const float* __restrict__ att, const float* __restrict__ bias,
                       float* __restrict__ hout) {
    int gid = blockIdx.x * blockDim.x + threadIdx.x;
    int n = gid >> 6, lane = gid & 63;
    if (n >= Nn) return;
    int s = off[n], t = off[n + 1];
    float xr_j = xr[n * 64 + lane];
    float We_j = We[lane], att_j = att[lane];
    float acc = 0.f, m_run = -1e30f, s_run = 0.f;
    for (int c = s; c < t; c += 64) {
        int cnt = min(64, t - c);
        float ce_l = (c + lane < t) ? cea[c + lane] : 0.f;
        int   cs_l = (c + lane < t) ? csrc[c + lane] : 0;
        // pass A: edge scores into lane slots
        float eslot = 0.f, cmax = -1e30f;
        for (int q = 0; q < cnt; ++q) {
            int sr = __shfl(cs_l, q);
            float ceav = __shfl(ce_l, q);
            float v = xl[sr * 64 + lane];
            float mm = v + xr_j + ceav * We_j;
            mm = mm > 0.f ? mm : 0.2f * mm;
            float pv = mm * att_j;
#pragma unroll
            for (int o = 32; o > 0; o >>= 1) pv += __shfl_xor(pv, o);
            eslot = (lane == q) ? pv : eslot;
            cmax = fmaxf(cmax, pv);
        }
        // online rescale
        float m_new = fmaxf(m_run, cmax);
        float f = expf(m_run - m_new);
        acc *= f; s_run *= f;
        // pass B: weighted accumulate (rows L1-hot from pass A)
        for (int q = 0; q < cnt; ++q) {
            int sr = __shfl(cs_l, q);
            float e_p = __shfl(eslot, q);
            float w = expf(e_p - m_new);
            acc += w * xl[sr * 64 + lane];
            s_run += w;
        }
        m_run = m_new;
    }
    float o2 = (t > s) ? acc / s_run : 0.f;
    o2 += bias[lane];
    hout[n * 64 + lane] = o2 / (1.f + expf(-o2));  // silu
}

// ---------------- RK4 stage: LDS y-tile + 16-node register blocking ----------------
// block = 128 threads = 16 nodes. Stage y=h+cf*kprev into LDS once (coalesced),
// phase1: z[16][128]=tanh(y@W1+b1), thread k handles all 16 nodes;
// phase2: out[16][64]=z@W2+b2 + epilogue, thread (j, wg) handles 8 nodes.
template <int STAGE>
__global__ __launch_bounds__(128) void k_ode(float* __restrict__ h,
        const float* __restrict__ kprev,
        const float* __restrict__ W1, const float* __restrict__ b1,
        const float* __restrict__ W2, const float* __restrict__ b2,
        float* __restrict__ kout, float* __restrict__ ksum) {
    __shared__ float yt[16][64];
    __shared__ float zt[16][128];
    int t = threadIdx.x;
    int nb = blockIdx.x * 16;
    {   // cooperative stage: 1024 floats, 128 threads x 2 float4
        const float cf = (STAGE == 3) ? 1.0f : 0.5f;
#pragma unroll
        for (int r = 0; r < 2; ++r) {
            int f = t + r * 128;
            int nn = f >> 4, jj = (f & 15) * 4;
            float4 hv = *(const float4*)(h + (size_t)(nb + nn) * 64 + jj);
            if (STAGE != 0) {
                float4 kv = *(const float4*)(kprev + (size_t)(nb + nn) * 64 + jj);
                hv.x += cf * kv.x; hv.y += cf * kv.y; hv.z += cf * kv.z; hv.w += cf * kv.w;
            }
            *(float4*)&yt[nn][jj] = hv;
        }
    }
    __syncthreads();
    {   // phase 1: k = t (0..127), 16 nodes per thread
        int k = t;
        float acc1[16];
#pragma unroll
        for (int q = 0; q < 16; ++q) acc1[q] = b1[k];
        for (int i4 = 0; i4 < 16; ++i4) {
            float wv4[4];
#pragma unroll
            for (int u = 0; u < 4; ++u) wv4[u] = W1[(i4 * 4 + u) * 128 + k];  // coalesced
#pragma unroll
            for (int half = 0; half < 2; ++half) {
                float4 yv[8];
#pragma unroll
                for (int q8 = 0; q8 < 8; ++q8)
                    yv[q8] = *(const float4*)&yt[half * 8 + q8][i4 * 4];      // LDS broadcast
#pragma unroll
                for (int u = 0; u < 4; ++u)
#pragma unroll
                    for (int q8 = 0; q8 < 8; ++q8)
                        acc1[half * 8 + q8] += ((const float*)&yv[q8])[u] * wv4[u];
            }
        }
#pragma unroll
        for (int q = 0; q < 16; ++q) zt[q][k] = tanhf(acc1[q]);
    }
    __syncthreads();
    {   // phase 2: j = t&63, wg = t>>6 (2 groups x 8 nodes)
        int j = t & 63, wg = t >> 6;
        float acc2[8];
#pragma unroll
        for (int q = 0; q < 8; ++q) acc2[q] = b2[j];
        for (int k4 = 0; k4 < 32; ++k4) {
            float wv2[4];
#pragma unroll
            for (int u = 0; u < 4; ++u) wv2[u] = W2[(k4 * 4 + u) * 64 + j];   // coalesced
            float4 zv[8];
#pragma unroll
            for (int q = 0; q < 8; ++q)
                zv[q] = *(const float4*)&zt[wg * 8 + q][k4 * 4];              // LDS broadcast
#pragma unroll
            for (int u = 0; u < 4; ++u)
#pragma unroll
                for (int q = 0; q < 8; ++q)
                    acc2[q] += ((const float*)&zv[q])[u] * wv2[u];
        }
#pragma unroll
        for (int q = 0; q < 8; ++q) {
            size_t gi = (size_t)(nb + wg * 8 + q) * 64 + j;
            if (STAGE == 0)      { kout[gi] = acc2[q]; ksum[gi] = acc2[q]; }
            else if (STAGE == 3) { h[gi] = h[gi] + (ksum[gi] + acc2[q]) * (1.f / 6.f); }
            else                 { kout[gi] = acc2[q]; ksum[gi] += 2.f * acc2[q]; }
        }
    }
}

// ---------------- pooling ----------------
__global__ void k_binit(int* __restrict__ gs, int* __restrict__ ge) {
    int b = threadIdx.x;
    if (b < Bb) { gs[b] = 0; ge[b] = 0; }
}

__global__ void k_bounds(const int* __restrict__ batch, int* __restrict__ gs,
                         int* __restrict__ ge) {
    int n = blockIdx.x * blockDim.x + threadIdx.x;
    if (n >= Nn) return;
    int b = batch[n];
    if (n == 0 || batch[n - 1] != b) gs[b] = n;
    if (n == Nn - 1 || batch[n + 1] != b) ge[b] = n + 1;
}

__global__ void k_pool(const float* __restrict__ h, const int* __restrict__ gs,
                       const int* __restrict__ ge, float* __restrict__ g) {
    int b = blockIdx.x;
    int s = gs[b], e = ge[b];
    int w = threadIdx.x >> 6, lane = threadIdx.x & 63;
    float sum = 0.f, mx = -1e30f;
    for (int n = s + w; n < e; n += 4) {
        float v = h[n * Hh + lane];
        sum += v;
        mx = fmaxf(mx, v);
    }
    __shared__ float ssum[4][64], smx[4][64];
    ssum[w][lane] = sum;
    smx[w][lane] = mx;
    __syncthreads();
    if (threadIdx.x < 64) {
        int j = threadIdx.x;
        float su = ssum[0][j] + ssum[1][j] + ssum[2][j] + ssum[3][j];
        float m2 = fmaxf(fmaxf(smx[0][j], smx[1][j]), fmaxf(smx[2][j], smx[3][j]));
        int cnt = e - s;
        g[b * 2 * Hh + j] = (cnt > 0) ? su / (float)cnt : 0.f;
        g[b * 2 * Hh + Hh + j] = (cnt > 0) ? m2 : 0.f;
    }
}

// ---------------- predictor head: wave per graph ----------------
__global__ void k_pred(const float* __restrict__ g, const float* __restrict__ W1,
                       const float* __restrict__ b1, const float* __restrict__ W2,
                       const float* __restrict__ b2, float* __restrict__ out) {
    int gid = blockIdx.x * blockDim.x + threadIdx.x;
    int b = gid >> 6, lane = gid & 63;
    if (b >= Bb) return;
    int hh = lane & 31, half = lane >> 5;
    const float* gr = g + b * 2 * Hh + half * Hh;
    float a = 0.f;
#pragma unroll 8
    for (int i = 0; i < Hh; ++i) a += gr[i] * W1[(half * Hh + i) * 32 + hh];
    a += __shfl_xor(a, 32);
    a += b1[hh];
    float sl = a / (1.f + expf(-a));
    float partial = (half == 0) ? sl * W2[hh] : 0.f;
#pragma unroll
    for (int o = 32; o > 0; o >>= 1) partial += __shfl_xor(partial, o);
    if (lane == 0) out[b] = partial + b2[0];
}

extern "C" void kernel_launch(void* const* d_in, const int* in_sizes, int n_in,
                              void* d_out, int out_size, void* d_ws, size_t ws_size,
                              hipStream_t stream) {
    const float* x     = (const float*)d_in[0];
    const int*   ei    = (const int*)d_in[1];
    const float* ea    = (const float*)d_in[2];
    const int*   batch = (const int*)d_in[3];
    const float* embW  = (const float*)d_in[4];
    const float* embB  = (const float*)d_in[5];
    const float* c1Wl = (const float*)d_in[6];  const float* c1bl = (const float*)d_in[7];
    const float* c1Wr = (const float*)d_in[8];  const float* c1br = (const float*)d_in[9];
    const float* c1We = (const float*)d_in[10]; const float* c1att = (const float*)d_in[11];
    const float* c1bias = (const float*)d_in[12];
    const float* c2Wl = (const float*)d_in[13]; const float* c2bl = (const float*)d_in[14];
    const float* c2Wr = (const float*)d_in[15]; const float* c2br = (const float*)d_in[16];
    const float* c2We = (const float*)d_in[17]; const float* c2att = (const float*)d_in[18];
    const float* c2bias = (const float*)d_in[19];
    const float* oW1 = (const float*)d_in[20]; const float* ob1 = (const float*)d_in[21];
    const float* oW2 = (const float*)d_in[22]; const float* ob2 = (const float*)d_in[23];
    const float* pW1 = (const float*)d_in[24]; const float* pb1 = (const float*)d_in[25];
    const float* pW2 = (const float*)d_in[26]; const float* pb2 = (const float*)d_in[27];
    float* out = (float*)d_out;

    // workspace layout (floats)
    float* fws = (float*)d_ws;
    size_t NH = (size_t)Nn * Hh;           // 3.2M
    float* h    = fws;
    float* xl   = fws + NH;                // RK4: kA
    float* xr   = fws + 2 * NH;            // RK4: kB
    float* ksum = fws + 3 * NH;
    float* cea  = fws + 4 * NH;            // [Ee]
    int*   csrc = (int*)(cea + Ee);        // [Ee]
    float* g    = (float*)(csrc + Ee);     // [Bb*128]
    int* iws = (int*)(g + (size_t)Bb * 128);
    int* counts = iws;                     // [Nn]
    int* off    = counts + Nn;             // [Nn+1]
    int* cursor = off + Nn + 1;            // [Nn]
    int* chk    = cursor + Nn;             // [128]
    int* gs     = chk + 128;               // [Bb]
    int* ge     = gs + Bb;                 // [Bb]

    const int* src = ei;
    const int* dst = ei + Ee;

    hipMemsetAsync(counts, 0, Nn * sizeof(int), stream);
    k_embed<<<(Nn * Hh + TPB - 1) / TPB, TPB, 0, stream>>>(x, embW, embB, h);
    k_hist<<<(Ee + TPB - 1) / TPB, TPB, 0, stream>>>(dst, counts);
    k_scan1<<<(Nn + CHUNK - 1) / CHUNK, CHUNK, 0, stream>>>(counts, off, chk);
    k_scan2<<<1, 64, 0, stream>>>(chk, (Nn + CHUNK - 1) / CHUNK);
    k_scan3<<<(Nn + 1 + TPB - 1) / TPB, TPB, 0, stream>>>(off, chk);
    k_copy<<<(Nn + TPB - 1) / TPB, TPB, 0, stream>>>(off, cursor);
    k_scatter<<<(Ee + TPB - 1) / TPB, TPB, 0, stream>>>(src, dst, ea, cursor, csrc, cea);

    // conv1
    k_lin<<<Nn / 16, TPB, 0, stream>>>(h, c1Wl, c1bl, c1Wr, c1br, xl, xr);
    k_conv<<<(Nn * 64 + TPB - 1) / TPB, TPB, 0, stream>>>(xl, xr, cea, csrc, off, c1We, c1att, c1bias, h);

    // conv2
    k_lin<<<Nn / 16, TPB, 0, stream>>>(h, c2Wl, c2bl, c2Wr, c2br, xl, xr);
    k_conv<<<(Nn * 64 + TPB - 1) / TPB, TPB, 0, stream>>>(xl, xr, cea, csrc, off, c2We, c2att, c2bias, h);

    // RK4: fused per-stage kernels. k1=xl, k2=xr, k3=xl, k4 consumed in-place.
    int gOde = Nn / 16;  // 3125 blocks of 128 threads
    k_ode<0><<<gOde, 128, 0, stream>>>(h, h,  oW1, ob1, oW2, ob2, xl, ksum);
    k_ode<1><<<gOde, 128, 0, stream>>>(h, xl, oW1, ob1, oW2, ob2, xr, ksum);
    k_ode<2><<<gOde, 128, 0, stream>>>(h, xr, oW1, ob1, oW2, ob2, xl, ksum);
    k_ode<3><<<gOde, 128, 0, stream>>>(h, xl, oW1, ob1, oW2, ob2, xr, ksum);

    // pooling + head
    k_binit<<<1, Bb, 0, stream>>>(gs, ge);
    k_bounds<<<(Nn + TPB - 1) / TPB, TPB, 0, stream>>>(batch, gs, ge);
    k_pool<<<Bb, 256, 0, stream>>>(h, gs, ge, g);
    k_pred<<<(Bb * 64 + TPB - 1) / TPB, TPB, 0, stream>>>(g, pW1, pb1, pW2, pb2, out);
}

// Round 10
// 599.144 us; speedup vs baseline: 4.9100x; 1.2319x over previous
//
#include <hip/hip_runtime.h>
#include <math.h>

// Problem constants
#define Nn 50000
#define Ee 800000
#define Bb 256
#define Hh 64
#define TPB 256
#define CHUNK 512

// ---------------- embed: h = x @ W(4x64) + b ----------------
__global__ void k_embed(const float* __restrict__ x, const float* __restrict__ W,
                        const float* __restrict__ b, float* __restrict__ h) {
    int idx = blockIdx.x * blockDim.x + threadIdx.x;
    if (idx >= Nn * Hh) return;
    int n = idx >> 6, j = idx & 63;
    float acc = b[j];
#pragma unroll
    for (int d = 0; d < 4; ++d) acc += x[n * 4 + d] * W[d * Hh + j];
    h[idx] = acc;
}

// ---------------- CSR build ----------------
__global__ void k_hist(const int* __restrict__ dst, int* __restrict__ counts) {
    int e = blockIdx.x * blockDim.x + threadIdx.x;
    if (e < Ee) atomicAdd(&counts[dst[e]], 1);
}

__global__ void k_scan1(const int* __restrict__ counts, int* __restrict__ off,
                        int* __restrict__ chunksum) {
    __shared__ int s[CHUNK];
    int t = threadIdx.x;
    int base = blockIdx.x * CHUNK;
    int v = (base + t < Nn) ? counts[base + t] : 0;
    s[t] = v;
    __syncthreads();
    for (int d = 1; d < CHUNK; d <<= 1) {
        int u = (t >= d) ? s[t - d] : 0;
        __syncthreads();
        s[t] += u;
        __syncthreads();
    }
    if (base + t < Nn) off[base + t + 1] = s[t];
    if (t == CHUNK - 1) chunksum[blockIdx.x] = s[t];
}

__global__ void k_scan2(int* __restrict__ chunksum, int nch) {
    if (blockIdx.x == 0 && threadIdx.x == 0) {
        int run = 0;
        for (int i = 0; i < nch; ++i) { int v = chunksum[i]; chunksum[i] = run; run += v; }
    }
}

__global__ void k_scan3(int* __restrict__ off, const int* __restrict__ chunkoff) {
    int i = blockIdx.x * blockDim.x + threadIdx.x;
    if (i > Nn) return;
    if (i == 0) { off[0] = 0; return; }
    off[i] += chunkoff[(i - 1) >> 9];  // CHUNK=512
}

__global__ void k_copy(const int* __restrict__ off, int* __restrict__ cursor) {
    int n = blockIdx.x * blockDim.x + threadIdx.x;
    if (n < Nn) cursor[n] = off[n];
}

__global__ void k_scatter(const int* __restrict__ src, const int* __restrict__ dst,
                          const float* __restrict__ ea, int* __restrict__ cursor,
                          int* __restrict__ csrc, float* __restrict__ cea) {
    int e = blockIdx.x * blockDim.x + threadIdx.x;
    if (e >= Ee) return;
    int d = dst[e];
    int p = atomicAdd(&cursor[d], 1);
    csrc[p] = src[e];
    cea[p] = ea[e];
}

// ---------------- conv linear: lane = output col (coalesced weights), 4 nodes/thread ----
__global__ __launch_bounds__(256) void k_lin(const float* __restrict__ h,
                      const float* __restrict__ Wl, const float* __restrict__ bl,
                      const float* __restrict__ Wr, const float* __restrict__ br,
                      float* __restrict__ xl, float* __restrict__ xr) {
    int lane = threadIdx.x & 63, w = threadIdx.x >> 6;
    int n0 = blockIdx.x * 16 + w * 4;      // 4 nodes per wave, 16 per block
    float al[4], ar[4];
#pragma unroll
    for (int q = 0; q < 4; ++q) { al[q] = bl[lane]; ar[q] = br[lane]; }
    for (int i4 = 0; i4 < 16; ++i4) {
        float4 hv[4];
#pragma unroll
        for (int q = 0; q < 4; ++q)
            hv[q] = *(const float4*)(h + (n0 + q) * 64 + i4 * 4);   // wave-uniform broadcast
#pragma unroll
        for (int u = 0; u < 4; ++u) {
            int i = i4 * 4 + u;
            float wlv = Wl[i * 64 + lane];   // coalesced across lanes
            float wrv = Wr[i * 64 + lane];
#pragma unroll
            for (int q = 0; q < 4; ++q) {
                float hq = ((const float*)&hv[q])[u];
                al[q] += hq * wlv;
                ar[q] += hq * wrv;
            }
        }
    }
#pragma unroll
    for (int q = 0; q < 4; ++q) {
        xl[(n0 + q) * 64 + lane] = al[q];
        xr[(n0 + q) * 64 + lane] = ar[q];
    }
}

// ---------------- fused GATv2 conv, 16-lane-group float4 layout ----------------
// Wave per node; 4 groups x 16 lanes; group g owns edge c+g, lane holds float4
// feature slice. Single gather per edge: row reused for score AND accumulate.
__global__ void k_conv(const float* __restrict__ xl, const float* __restrict__ xr,
                       const float* __restrict__ cea, const int* __restrict__ csrc,
                       const int* __restrict__ off, const float* __restrict__ We,
                       const float* __restrict__ att, const float* __restrict__ bias,
                       float* __restrict__ hout) {
    int gid = blockIdx.x * blockDim.x + threadIdx.x;
    int n = gid >> 6, lane = gid & 63;
    if (n >= Nn) return;
    int g = lane >> 4, l16 = lane & 15;
    int s = off[n], t = off[n + 1];
    float4 xr4 = *(const float4*)(xr + (size_t)n * 64 + l16 * 4);
    float4 We4 = *(const float4*)(We + l16 * 4);
    float4 at4 = *(const float4*)(att + l16 * 4);
    float4 acc = make_float4(0.f, 0.f, 0.f, 0.f);
    float m_run = -1e30f, s_run = 0.f;
    for (int c = s; c < t; c += 4) {
        int e = c + g;
        bool valid = e < t;
        int sr = valid ? csrc[e] : csrc[c];
        float ceav = valid ? cea[e] : 0.f;
        float4 row = *(const float4*)(xl + (size_t)sr * 64 + l16 * 4);
        // score partial: leakyrelu(row + xr + ceav*We) . att
        float mx_ = row.x + xr4.x + ceav * We4.x;
        float my_ = row.y + xr4.y + ceav * We4.y;
        float mz_ = row.z + xr4.z + ceav * We4.z;
        float mw_ = row.w + xr4.w + ceav * We4.w;
        mx_ = mx_ > 0.f ? mx_ : 0.2f * mx_;
        my_ = my_ > 0.f ? my_ : 0.2f * my_;
        mz_ = mz_ > 0.f ? mz_ : 0.2f * mz_;
        mw_ = mw_ > 0.f ? mw_ : 0.2f * mw_;
        float pv = mx_ * at4.x + my_ * at4.y + mz_ * at4.z + mw_ * at4.w;
        // intra-group reduce (16 lanes)
#pragma unroll
        for (int o = 1; o < 16; o <<= 1) pv += __shfl_xor(pv, o);
        float ee = valid ? pv : -1e30f;
        // chunk max across groups
        float cm = ee;
        cm = fmaxf(cm, __shfl_xor(cm, 16));
        cm = fmaxf(cm, __shfl_xor(cm, 32));
        float m_new = fmaxf(m_run, cm);
        float f = __expf(m_run - m_new);
        acc.x *= f; acc.y *= f; acc.z *= f; acc.w *= f; s_run *= f;
        float w = __expf(ee - m_new);     // 0 for invalid lanes
        acc.x += w * row.x; acc.y += w * row.y;
        acc.z += w * row.z; acc.w += w * row.w;
        s_run += w;
        m_run = m_new;
    }
    // cross-group combine (groups at lane^16, lane^32)
#pragma unroll
    for (int o = 16; o <= 32; o <<= 1) {
        acc.x += __shfl_xor(acc.x, o); acc.y += __shfl_xor(acc.y, o);
        acc.z += __shfl_xor(acc.z, o); acc.w += __shfl_xor(acc.w, o);
        s_run += __shfl_xor(s_run, o);
    }
    float4 b4 = *(const float4*)(bias + l16 * 4);
    float inv = (t > s) ? 1.f / s_run : 0.f;
    float4 o4;
    o4.x = acc.x * inv + b4.x; o4.y = acc.y * inv + b4.y;
    o4.z = acc.z * inv + b4.z; o4.w = acc.w * inv + b4.w;
    o4.x = o4.x / (1.f + __expf(-o4.x));
    o4.y = o4.y / (1.f + __expf(-o4.y));
    o4.z = o4.z / (1.f + __expf(-o4.z));
    o4.w = o4.w / (1.f + __expf(-o4.w));
    if (lane < 16) *(float4*)(hout + (size_t)n * 64 + l16 * 4) = o4;
}

// ---------------- RK4 stage: LDS y-tile + 16-node register blocking ----------------
template <int STAGE>
__global__ __launch_bounds__(128) void k_ode(float* __restrict__ h,
        const float* __restrict__ kprev,
        const float* __restrict__ W1, const float* __restrict__ b1,
        const float* __restrict__ W2, const float* __restrict__ b2,
        float* __restrict__ kout, float* __restrict__ ksum) {
    __shared__ float yt[16][64];
    __shared__ float zt[16][128];
    int t = threadIdx.x;
    int nb = blockIdx.x * 16;
    {   // cooperative stage: 1024 floats, 128 threads x 2 float4
        const float cf = (STAGE == 3) ? 1.0f : 0.5f;
#pragma unroll
        for (int r = 0; r < 2; ++r) {
            int f = t + r * 128;
            int nn = f >> 4, jj = (f & 15) * 4;
            float4 hv = *(const float4*)(h + (size_t)(nb + nn) * 64 + jj);
            if (STAGE != 0) {
                float4 kv = *(const float4*)(kprev + (size_t)(nb + nn) * 64 + jj);
                hv.x += cf * kv.x; hv.y += cf * kv.y; hv.z += cf * kv.z; hv.w += cf * kv.w;
            }
            *(float4*)&yt[nn][jj] = hv;
        }
    }
    __syncthreads();
    {   // phase 1: k = t (0..127), 16 nodes per thread
        int k = t;
        float acc1[16];
#pragma unroll
        for (int q = 0; q < 16; ++q) acc1[q] = b1[k];
        for (int i4 = 0; i4 < 16; ++i4) {
            float wv4[4];
#pragma unroll
            for (int u = 0; u < 4; ++u) wv4[u] = W1[(i4 * 4 + u) * 128 + k];  // coalesced
#pragma unroll
            for (int half = 0; half < 2; ++half) {
                float4 yv[8];
#pragma unroll
                for (int q8 = 0; q8 < 8; ++q8)
                    yv[q8] = *(const float4*)&yt[half * 8 + q8][i4 * 4];      // LDS broadcast
#pragma unroll
                for (int u = 0; u < 4; ++u)
#pragma unroll
                    for (int q8 = 0; q8 < 8; ++q8)
                        acc1[half * 8 + q8] += ((const float*)&yv[q8])[u] * wv4[u];
            }
        }
#pragma unroll
        for (int q = 0; q < 16; ++q) zt[q][k] = tanhf(acc1[q]);
    }
    __syncthreads();
    {   // phase 2: j = t&63, wg = t>>6 (2 groups x 8 nodes)
        int j = t & 63, wg = t >> 6;
        float acc2[8];
#pragma unroll
        for (int q = 0; q < 8; ++q) acc2[q] = b2[j];
        for (int k4 = 0; k4 < 32; ++k4) {
            float wv2[4];
#pragma unroll
            for (int u = 0; u < 4; ++u) wv2[u] = W2[(k4 * 4 + u) * 64 + j];   // coalesced
            float4 zv[8];
#pragma unroll
            for (int q = 0; q < 8; ++q)
                zv[q] = *(const float4*)&zt[wg * 8 + q][k4 * 4];              // LDS broadcast
#pragma unroll
            for (int u = 0; u < 4; ++u)
#pragma unroll
                for (int q = 0; q < 8; ++q)
                    acc2[q] += ((const float*)&zv[q])[u] * wv2[u];
        }
#pragma unroll
        for (int q = 0; q < 8; ++q) {
            size_t gi = (size_t)(nb + wg * 8 + q) * 64 + j;
            if (STAGE == 0)      { kout[gi] = acc2[q]; ksum[gi] = acc2[q]; }
            else if (STAGE == 3) { h[gi] = h[gi] + (ksum[gi] + acc2[q]) * (1.f / 6.f); }
            else                 { kout[gi] = acc2[q]; ksum[gi] += 2.f * acc2[q]; }
        }
    }
}

// ---------------- pooling ----------------
__global__ void k_binit(int* __restrict__ gs, int* __restrict__ ge) {
    int b = threadIdx.x;
    if (b < Bb) { gs[b] = 0; ge[b] = 0; }
}

__global__ void k_bounds(const int* __restrict__ batch, int* __restrict__ gs,
                         int* __restrict__ ge) {
    int n = blockIdx.x * blockDim.x + threadIdx.x;
    if (n >= Nn) return;
    int b = batch[n];
    if (n == 0 || batch[n - 1] != b) gs[b] = n;
    if (n == Nn - 1 || batch[n + 1] != b) ge[b] = n + 1;
}

__global__ void k_pool(const float* __restrict__ h, const int* __restrict__ gs,
                       const int* __restrict__ ge, float* __restrict__ g) {
    int b = blockIdx.x;
    int s = gs[b], e = ge[b];
    int w = threadIdx.x >> 6, lane = threadIdx.x & 63;
    float sum = 0.f, mx = -1e30f;
    for (int n = s + w; n < e; n += 4) {
        float v = h[n * Hh + lane];
        sum += v;
        mx = fmaxf(mx, v);
    }
    __shared__ float ssum[4][64], smx[4][64];
    ssum[w][lane] = sum;
    smx[w][lane] = mx;
    __syncthreads();
    if (threadIdx.x < 64) {
        int j = threadIdx.x;
        float su = ssum[0][j] + ssum[1][j] + ssum[2][j] + ssum[3][j];
        float m2 = fmaxf(fmaxf(smx[0][j], smx[1][j]), fmaxf(smx[2][j], smx[3][j]));
        int cnt = e - s;
        g[b * 2 * Hh + j] = (cnt > 0) ? su / (float)cnt : 0.f;
        g[b * 2 * Hh + Hh + j] = (cnt > 0) ? m2 : 0.f;
    }
}

// ---------------- predictor head: wave per graph ----------------
__global__ void k_pred(const float* __restrict__ g, const float* __restrict__ W1,
                       const float* __restrict__ b1, const float* __restrict__ W2,
                       const float* __restrict__ b2, float* __restrict__ out) {
    int gid = blockIdx.x * blockDim.x + threadIdx.x;
    int b = gid >> 6, lane = gid & 63;
    if (b >= Bb) return;
    int hh = lane & 31, half = lane >> 5;
    const float* gr = g + b * 2 * Hh + half * Hh;
    float a = 0.f;
#pragma unroll 8
    for (int i = 0; i < Hh; ++i) a += gr[i] * W1[(half * Hh + i) * 32 + hh];
    a += __shfl_xor(a, 32);
    a += b1[hh];
    float sl = a / (1.f + expf(-a));
    float partial = (half == 0) ? sl * W2[hh] : 0.f;
#pragma unroll
    for (int o = 32; o > 0; o >>= 1) partial += __shfl_xor(partial, o);
    if (lane == 0) out[b] = partial + b2[0];
}

extern "C" void kernel_launch(void* const* d_in, const int* in_sizes, int n_in,
                              void* d_out, int out_size, void* d_ws, size_t ws_size,
                              hipStream_t stream) {
    const float* x     = (const float*)d_in[0];
    const int*   ei    = (const int*)d_in[1];
    const float* ea    = (const float*)d_in[2];
    const int*   batch = (const int*)d_in[3];
    const float* embW  = (const float*)d_in[4];
    const float* embB  = (const float*)d_in[5];
    const float* c1Wl = (const float*)d_in[6];  const float* c1bl = (const float*)d_in[7];
    const float* c1Wr = (const float*)d_in[8];  const float* c1br = (const float*)d_in[9];
    const float* c1We = (const float*)d_in[10]; const float* c1att = (const float*)d_in[11];
    const float* c1bias = (const float*)d_in[12];
    const float* c2Wl = (const float*)d_in[13]; const float* c2bl = (const float*)d_in[14];
    const float* c2Wr = (const float*)d_in[15]; const float* c2br = (const float*)d_in[16];
    const float* c2We = (const float*)d_in[17]; const float* c2att = (const float*)d_in[18];
    const float* c2bias = (const float*)d_in[19];
    const float* oW1 = (const float*)d_in[20]; const float* ob1 = (const float*)d_in[21];
    const float* oW2 = (const float*)d_in[22]; const float* ob2 = (const float*)d_in[23];
    const float* pW1 = (const float*)d_in[24]; const float* pb1 = (const float*)d_in[25];
    const float* pW2 = (const float*)d_in[26]; const float* pb2 = (const float*)d_in[27];
    float* out = (float*)d_out;

    // workspace layout (floats)
    float* fws = (float*)d_ws;
    size_t NH = (size_t)Nn * Hh;           // 3.2M
    float* h    = fws;
    float* xl   = fws + NH;                // RK4: kA
    float* xr   = fws + 2 * NH;            // RK4: kB
    float* ksum = fws + 3 * NH;
    float* cea  = fws + 4 * NH;            // [Ee]
    int*   csrc = (int*)(cea + Ee);        // [Ee]
    float* g    = (float*)(csrc + Ee);     // [Bb*128]
    int* iws = (int*)(g + (size_t)Bb * 128);
    int* counts = iws;                     // [Nn]
    int* off    = counts + Nn;             // [Nn+1]
    int* cursor = off + Nn + 1;            // [Nn]
    int* chk    = cursor + Nn;             // [128]
    int* gs     = chk + 128;               // [Bb]
    int* ge     = gs + Bb;                 // [Bb]

    const int* src = ei;
    const int* dst = ei + Ee;

    hipMemsetAsync(counts, 0, Nn * sizeof(int), stream);
    k_embed<<<(Nn * Hh + TPB - 1) / TPB, TPB, 0, stream>>>(x, embW, embB, h);
    k_hist<<<(Ee + TPB - 1) / TPB, TPB, 0, stream>>>(dst, counts);
    k_scan1<<<(Nn + CHUNK - 1) / CHUNK, CHUNK, 0, stream>>>(counts, off, chk);
    k_scan2<<<1, 64, 0, stream>>>(chk, (Nn + CHUNK - 1) / CHUNK);
    k_scan3<<<(Nn + 1 + TPB - 1) / TPB, TPB, 0, stream>>>(off, chk);
    k_copy<<<(Nn + TPB - 1) / TPB, TPB, 0, stream>>>(off, cursor);
    k_scatter<<<(Ee + TPB - 1) / TPB, TPB, 0, stream>>>(src, dst, ea, cursor, csrc, cea);

    // conv1
    k_lin<<<Nn / 16, TPB, 0, stream>>>(h, c1Wl, c1bl, c1Wr, c1br, xl, xr);
    k_conv<<<(Nn * 64 + TPB - 1) / TPB, TPB, 0, stream>>>(xl, xr, cea, csrc, off, c1We, c1att, c1bias, h);

    // conv2
    k_lin<<<Nn / 16, TPB, 0, stream>>>(h, c2Wl, c2bl, c2Wr, c2br, xl, xr);
    k_conv<<<(Nn * 64 + TPB - 1) / TPB, TPB, 0, stream>>>(xl, xr, cea, csrc, off, c2We, c2att, c2bias, h);

    // RK4: fused per-stage kernels. k1=xl, k2=xr, k3=xl, k4 consumed in-place.
    int gOde = Nn / 16;  // 3125 blocks of 128 threads
    k_ode<0><<<gOde, 128, 0, stream>>>(h, h,  oW1, ob1, oW2, ob2, xl, ksum);
    k_ode<1><<<gOde, 128, 0, stream>>>(h, xl, oW1, ob1, oW2, ob2, xr, ksum);
    k_ode<2><<<gOde, 128, 0, stream>>>(h, xr, oW1, ob1, oW2, ob2, xl, ksum);
    k_ode<3><<<gOde, 128, 0, stream>>>(h, xl, oW1, ob1, oW2, ob2, xr, ksum);

    // pooling + head
    k_binit<<<1, Bb, 0, stream>>>(gs, ge);
    k_bounds<<<(Nn + TPB - 1) / TPB, TPB, 0, stream>>>(batch, gs, ge);
    k_pool<<<Bb, 256, 0, stream>>>(h, gs, ge, g);
    k_pred<<<(Bb * 64 + TPB - 1) / TPB, TPB, 0, stream>>>(g, pW1, pb1, pW2, pb2, out);
}

// Round 12
// 588.675 us; speedup vs baseline: 4.9973x; 1.0178x over previous
//
#include <hip/hip_runtime.h>
#include <math.h>

// Problem constants
#define Nn 50000
#define Ee 800000
#define Bb 256
#define Hh 64
#define TPB 256
#define CHUNK 512

// ---------------- embed: h = x @ W(4x64) + b ----------------
__global__ void k_embed(const float* __restrict__ x, const float* __restrict__ W,
                        const float* __restrict__ b, float* __restrict__ h) {
    int idx = blockIdx.x * blockDim.x + threadIdx.x;
    if (idx >= Nn * Hh) return;
    int n = idx >> 6, j = idx & 63;
    float acc = b[j];
#pragma unroll
    for (int d = 0; d < 4; ++d) acc += x[n * 4 + d] * W[d * Hh + j];
    h[idx] = acc;
}

// ---------------- CSR build ----------------
__global__ void k_hist(const int* __restrict__ dst, int* __restrict__ counts) {
    int e = blockIdx.x * blockDim.x + threadIdx.x;
    if (e < Ee) atomicAdd(&counts[dst[e]], 1);
}

__global__ void k_scan1(const int* __restrict__ counts, int* __restrict__ off,
                        int* __restrict__ chunksum) {
    __shared__ int s[CHUNK];
    int t = threadIdx.x;
    int base = blockIdx.x * CHUNK;
    int v = (base + t < Nn) ? counts[base + t] : 0;
    s[t] = v;
    __syncthreads();
    for (int d = 1; d < CHUNK; d <<= 1) {
        int u = (t >= d) ? s[t - d] : 0;
        __syncthreads();
        s[t] += u;
        __syncthreads();
    }
    if (base + t < Nn) off[base + t + 1] = s[t];
    if (t == CHUNK - 1) chunksum[blockIdx.x] = s[t];
}

__global__ void k_scan2(int* __restrict__ chunksum, int nch) {
    if (blockIdx.x == 0 && threadIdx.x == 0) {
        int run = 0;
        for (int i = 0; i < nch; ++i) { int v = chunksum[i]; chunksum[i] = run; run += v; }
    }
}

// scan3 + cursor init fused
__global__ void k_scan3(int* __restrict__ off, const int* __restrict__ chunkoff,
                        int* __restrict__ cursor) {
    int i = blockIdx.x * blockDim.x + threadIdx.x;
    if (i > Nn) return;
    int v;
    if (i == 0) { off[0] = 0; v = 0; }
    else {
        v = off[i] + chunkoff[(i - 1) >> 9];  // CHUNK=512
        off[i] = v;
    }
    if (i < Nn) cursor[i] = v;
}

// scatter: single 8B packed random write per edge (halves write-line traffic)
__global__ void k_scatter(const int* __restrict__ src, const int* __restrict__ dst,
                          const float* __restrict__ ea, int* __restrict__ cursor,
                          int2* __restrict__ epack) {
    int e = blockIdx.x * blockDim.x + threadIdx.x;
    if (e >= Ee) return;
    int d = dst[e];
    int p = atomicAdd(&cursor[d], 1);
    epack[p] = make_int2(src[e], __float_as_int(ea[e]));
}

// ---------------- conv linear: lane = output col (coalesced weights), 4 nodes/thread ----
__global__ __launch_bounds__(256) void k_lin(const float* __restrict__ h,
                      const float* __restrict__ Wl, const float* __restrict__ bl,
                      const float* __restrict__ Wr, const float* __restrict__ br,
                      float* __restrict__ xl, float* __restrict__ xr) {
    int lane = threadIdx.x & 63, w = threadIdx.x >> 6;
    int n0 = blockIdx.x * 16 + w * 4;      // 4 nodes per wave, 16 per block
    float al[4], ar[4];
#pragma unroll
    for (int q = 0; q < 4; ++q) { al[q] = bl[lane]; ar[q] = br[lane]; }
    for (int i4 = 0; i4 < 16; ++i4) {
        float4 hv[4];
#pragma unroll
        for (int q = 0; q < 4; ++q)
            hv[q] = *(const float4*)(h + (n0 + q) * 64 + i4 * 4);   // wave-uniform broadcast
#pragma unroll
        for (int u = 0; u < 4; ++u) {
            int i = i4 * 4 + u;
            float wlv = Wl[i * 64 + lane];   // coalesced across lanes
            float wrv = Wr[i * 64 + lane];
#pragma unroll
            for (int q = 0; q < 4; ++q) {
                float hq = ((const float*)&hv[q])[u];
                al[q] += hq * wlv;
                ar[q] += hq * wrv;
            }
        }
    }
#pragma unroll
    for (int q = 0; q < 4; ++q) {
        xl[(n0 + q) * 64 + lane] = al[q];
        xr[(n0 + q) * 64 + lane] = ar[q];
    }
}

// ---------------- fused GATv2 conv, 16-lane-group float4 layout ----------------
// Wave per node; 4 groups x 16 lanes; group g owns edge c+g, lane holds float4
// feature slice. Single gather per edge: row reused for score AND accumulate.
__global__ void k_conv(const float* __restrict__ xl, const float* __restrict__ xr,
                       const int2* __restrict__ epack, const int* __restrict__ off,
                       const float* __restrict__ We, const float* __restrict__ att,
                       const float* __restrict__ bias, float* __restrict__ hout) {
    int gid = blockIdx.x * blockDim.x + threadIdx.x;
    int n = gid >> 6, lane = gid & 63;
    if (n >= Nn) return;
    int g = lane >> 4, l16 = lane & 15;
    int s = off[n], t = off[n + 1];
    float4 xr4 = *(const float4*)(xr + (size_t)n * 64 + l16 * 4);
    float4 We4 = *(const float4*)(We + l16 * 4);
    float4 at4 = *(const float4*)(att + l16 * 4);
    float4 acc = make_float4(0.f, 0.f, 0.f, 0.f);
    float m_run = -1e30f, s_run = 0.f;
    for (int c = s; c < t; c += 4) {
        int e = c + g;
        bool valid = e < t;
        int2 pk = valid ? epack[e] : epack[c];
        int sr = pk.x;
        float ceav = valid ? __int_as_float(pk.y) : 0.f;
        float4 row = *(const float4*)(xl + (size_t)sr * 64 + l16 * 4);
        // score partial: leakyrelu(row + xr + ceav*We) . att
        float mx_ = row.x + xr4.x + ceav * We4.x;
        float my_ = row.y + xr4.y + ceav * We4.y;
        float mz_ = row.z + xr4.z + ceav * We4.z;
        float mw_ = row.w + xr4.w + ceav * We4.w;
        mx_ = mx_ > 0.f ? mx_ : 0.2f * mx_;
        my_ = my_ > 0.f ? my_ : 0.2f * my_;
        mz_ = mz_ > 0.f ? mz_ : 0.2f * mz_;
        mw_ = mw_ > 0.f ? mw_ : 0.2f * mw_;
        float pv = mx_ * at4.x + my_ * at4.y + mz_ * at4.z + mw_ * at4.w;
        // intra-group reduce (16 lanes)
#pragma unroll
        for (int o = 1; o < 16; o <<= 1) pv += __shfl_xor(pv, o);
        float ee = valid ? pv : -1e30f;
        // chunk max across groups
        float cm = ee;
        cm = fmaxf(cm, __shfl_xor(cm, 16));
        cm = fmaxf(cm, __shfl_xor(cm, 32));
        float m_new = fmaxf(m_run, cm);
        float f = __expf(m_run - m_new);
        acc.x *= f; acc.y *= f; acc.z *= f; acc.w *= f; s_run *= f;
        float w = __expf(ee - m_new);     // 0 for invalid lanes
        acc.x += w * row.x; acc.y += w * row.y;
        acc.z += w * row.z; acc.w += w * row.w;
        s_run += w;
        m_run = m_new;
    }
    // cross-group combine (groups at lane^16, lane^32)
#pragma unroll
    for (int o = 16; o <= 32; o <<= 1) {
        acc.x += __shfl_xor(acc.x, o); acc.y += __shfl_xor(acc.y, o);
        acc.z += __shfl_xor(acc.z, o); acc.w += __shfl_xor(acc.w, o);
        s_run += __shfl_xor(s_run, o);
    }
    float4 b4 = *(const float4*)(bias + l16 * 4);
    float inv = (t > s) ? 1.f / s_run : 0.f;
    float4 o4;
    o4.x = acc.x * inv + b4.x; o4.y = acc.y * inv + b4.y;
    o4.z = acc.z * inv + b4.z; o4.w = acc.w * inv + b4.w;
    o4.x = o4.x / (1.f + __expf(-o4.x));
    o4.y = o4.y / (1.f + __expf(-o4.y));
    o4.z = o4.z / (1.f + __expf(-o4.z));
    o4.w = o4.w / (1.f + __expf(-o4.w));
    if (lane < 16) *(float4*)(hout + (size_t)n * 64 + l16 * 4) = o4;
}

// ---------------- RK4 stage: LDS y-tile + 16-node register blocking ----------------
template <int STAGE>
__global__ __launch_bounds__(128) void k_ode(float* __restrict__ h,
        const float* __restrict__ kprev,
        const float* __restrict__ W1, const float* __restrict__ b1,
        const float* __restrict__ W2, const float* __restrict__ b2,
        float* __restrict__ kout, float* __restrict__ ksum) {
    __shared__ float yt[16][64];
    __shared__ float zt[16][128];
    int t = threadIdx.x;
    int nb = blockIdx.x * 16;
    {   // cooperative stage: 1024 floats, 128 threads x 2 float4
        const float cf = (STAGE == 3) ? 1.0f : 0.5f;
#pragma unroll
        for (int r = 0; r < 2; ++r) {
            int f = t + r * 128;
            int nn = f >> 4, jj = (f & 15) * 4;
            float4 hv = *(const float4*)(h + (size_t)(nb + nn) * 64 + jj);
            if (STAGE != 0) {
                float4 kv = *(const float4*)(kprev + (size_t)(nb + nn) * 64 + jj);
                hv.x += cf * kv.x; hv.y += cf * kv.y; hv.z += cf * kv.z; hv.w += cf * kv.w;
            }
            *(float4*)&yt[nn][jj] = hv;
        }
    }
    __syncthreads();
    {   // phase 1: k = t (0..127), 16 nodes per thread
        int k = t;
        float acc1[16];
#pragma unroll
        for (int q = 0; q < 16; ++q) acc1[q] = b1[k];
        for (int i4 = 0; i4 < 16; ++i4) {
            float wv4[4];
#pragma unroll
            for (int u = 0; u < 4; ++u) wv4[u] = W1[(i4 * 4 + u) * 128 + k];  // coalesced
#pragma unroll
            for (int half = 0; half < 2; ++half) {
                float4 yv[8];
#pragma unroll
                for (int q8 = 0; q8 < 8; ++q8)
                    yv[q8] = *(const float4*)&yt[half * 8 + q8][i4 * 4];      // LDS broadcast
#pragma unroll
                for (int u = 0; u < 4; ++u)
#pragma unroll
                    for (int q8 = 0; q8 < 8; ++q8)
                        acc1[half * 8 + q8] += ((const float*)&yv[q8])[u] * wv4[u];
            }
        }
#pragma unroll
        for (int q = 0; q < 16; ++q) zt[q][k] = tanhf(acc1[q]);
    }
    __syncthreads();
    {   // phase 2: j = t&63, wg = t>>6 (2 groups x 8 nodes)
        int j = t & 63, wg = t >> 6;
        float acc2[8];
#pragma unroll
        for (int q = 0; q < 8; ++q) acc2[q] = b2[j];
        for (int k4 = 0; k4 < 32; ++k4) {
            float wv2[4];
#pragma unroll
            for (int u = 0; u < 4; ++u) wv2[u] = W2[(k4 * 4 + u) * 64 + j];   // coalesced
            float4 zv[8];
#pragma unroll
            for (int q = 0; q < 8; ++q)
                zv[q] = *(const float4*)&zt[wg * 8 + q][k4 * 4];              // LDS broadcast
#pragma unroll
            for (int u = 0; u < 4; ++u)
#pragma unroll
                for (int q = 0; q < 8; ++q)
                    acc2[q] += ((const float*)&zv[q])[u] * wv2[u];
        }
#pragma unroll
        for (int q = 0; q < 8; ++q) {
            size_t gi = (size_t)(nb + wg * 8 + q) * 64 + j;
            if (STAGE == 0)      { kout[gi] = acc2[q]; ksum[gi] = acc2[q]; }
            else if (STAGE == 3) { h[gi] = h[gi] + (ksum[gi] + acc2[q]) * (1.f / 6.f); }
            else                 { kout[gi] = acc2[q]; ksum[gi] += 2.f * acc2[q]; }
        }
    }
}

// ---------------- pooling ----------------
__global__ void k_binit(int* __restrict__ gs, int* __restrict__ ge) {
    int b = threadIdx.x;
    if (b < Bb) { gs[b] = 0; ge[b] = 0; }
}

__global__ void k_bounds(const int* __restrict__ batch, int* __restrict__ gs,
                         int* __restrict__ ge) {
    int n = blockIdx.x * blockDim.x + threadIdx.x;
    if (n >= Nn) return;
    int b = batch[n];
    if (n == 0 || batch[n - 1] != b) gs[b] = n;
    if (n == Nn - 1 || batch[n + 1] != b) ge[b] = n + 1;
}

__global__ void k_pool(const float* __restrict__ h, const int* __restrict__ gs,
                       const int* __restrict__ ge, float* __restrict__ g) {
    int b = blockIdx.x;
    int s = gs[b], e = ge[b];
    int w = threadIdx.x >> 6, lane = threadIdx.x & 63;
    float sum = 0.f, mx = -1e30f;
    for (int n = s + w; n < e; n += 4) {
        float v = h[n * Hh + lane];
        sum += v;
        mx = fmaxf(mx, v);
    }
    __shared__ float ssum[4][64], smx[4][64];
    ssum[w][lane] = sum;
    smx[w][lane] = mx;
    __syncthreads();
    if (threadIdx.x < 64) {
        int j = threadIdx.x;
        float su = ssum[0][j] + ssum[1][j] + ssum[2][j] + ssum[3][j];
        float m2 = fmaxf(fmaxf(smx[0][j], smx[1][j]), fmaxf(smx[2][j], smx[3][j]));
        int cnt = e - s;
        g[b * 2 * Hh + j] = (cnt > 0) ? su / (float)cnt : 0.f;
        g[b * 2 * Hh + Hh + j] = (cnt > 0) ? m2 : 0.f;
    }
}

// ---------------- predictor head: wave per graph ----------------
__global__ void k_pred(const float* __restrict__ g, const float* __restrict__ W1,
                       const float* __restrict__ b1, const float* __restrict__ W2,
                       const float* __restrict__ b2, float* __restrict__ out) {
    int gid = blockIdx.x * blockDim.x + threadIdx.x;
    int b = gid >> 6, lane = gid & 63;
    if (b >= Bb) return;
    int hh = lane & 31, half = lane >> 5;
    const float* gr = g + b * 2 * Hh + half * Hh;
    float a = 0.f;
#pragma unroll 8
    for (int i = 0; i < Hh; ++i) a += gr[i] * W1[(half * Hh + i) * 32 + hh];
    a += __shfl_xor(a, 32);
    a += b1[hh];
    float sl = a / (1.f + expf(-a));
    float partial = (half == 0) ? sl * W2[hh] : 0.f;
#pragma unroll
    for (int o = 32; o > 0; o >>= 1) partial += __shfl_xor(partial, o);
    if (lane == 0) out[b] = partial + b2[0];
}

extern "C" void kernel_launch(void* const* d_in, const int* in_sizes, int n_in,
                              void* d_out, int out_size, void* d_ws, size_t ws_size,
                              hipStream_t stream) {
    const float* x     = (const float*)d_in[0];
    const int*   ei    = (const int*)d_in[1];
    const float* ea    = (const float*)d_in[2];
    const int*   batch = (const int*)d_in[3];
    const float* embW  = (const float*)d_in[4];
    const float* embB  = (const float*)d_in[5];
    const float* c1Wl = (const float*)d_in[6];  const float* c1bl = (const float*)d_in[7];
    const float* c1Wr = (const float*)d_in[8];  const float* c1br = (const float*)d_in[9];
    const float* c1We = (const float*)d_in[10]; const float* c1att = (const float*)d_in[11];
    const float* c1bias = (const float*)d_in[12];
    const float* c2Wl = (const float*)d_in[13]; const float* c2bl = (const float*)d_in[14];
    const float* c2Wr = (const float*)d_in[15]; const float* c2br = (const float*)d_in[16];
    const float* c2We = (const float*)d_in[17]; const float* c2att = (const float*)d_in[18];
    const float* c2bias = (const float*)d_in[19];
    const float* oW1 = (const float*)d_in[20]; const float* ob1 = (const float*)d_in[21];
    const float* oW2 = (const float*)d_in[22]; const float* ob2 = (const float*)d_in[23];
    const float* pW1 = (const float*)d_in[24]; const float* pb1 = (const float*)d_in[25];
    const float* pW2 = (const float*)d_in[26]; const float* pb2 = (const float*)d_in[27];
    float* out = (float*)d_out;

    // workspace layout (floats)
    float* fws = (float*)d_ws;
    size_t NH = (size_t)Nn * Hh;           // 3.2M
    float* h    = fws;
    float* xl   = fws + NH;                // RK4: kA
    float* xr   = fws + 2 * NH;            // RK4: kB
    float* ksum = fws + 3 * NH;
    int2*  epack = (int2*)(fws + 4 * NH);  // [Ee] packed (src, ea)
    float* g    = (float*)(epack + Ee);    // [Bb*128]
    int* iws = (int*)(g + (size_t)Bb * 128);
    int* counts = iws;                     // [Nn]
    int* off    = counts + Nn;             // [Nn+1]
    int* cursor = off + Nn + 1;            // [Nn]
    int* chk    = cursor + Nn;             // [128]
    int* gs     = chk + 128;               // [Bb]
    int* ge     = gs + Bb;                 // [Bb]

    const int* src = ei;
    const int* dst = ei + Ee;

    hipMemsetAsync(counts, 0, Nn * sizeof(int), stream);
    k_embed<<<(Nn * Hh + TPB - 1) / TPB, TPB, 0, stream>>>(x, embW, embB, h);
    k_hist<<<(Ee + TPB - 1) / TPB, TPB, 0, stream>>>(dst, counts);
    k_scan1<<<(Nn + CHUNK - 1) / CHUNK, CHUNK, 0, stream>>>(counts, off, chk);
    k_scan2<<<1, 64, 0, stream>>>(chk, (Nn + CHUNK - 1) / CHUNK);
    k_scan3<<<(Nn + 1 + TPB - 1) / TPB, TPB, 0, stream>>>(off, chk, cursor);
    k_scatter<<<(Ee + TPB - 1) / TPB, TPB, 0, stream>>>(src, dst, ea, cursor, epack);

    // conv1
    k_lin<<<Nn / 16, TPB, 0, stream>>>(h, c1Wl, c1bl, c1Wr, c1br, xl, xr);
    k_conv<<<(Nn * 64 + TPB - 1) / TPB, TPB, 0, stream>>>(xl, xr, epack, off, c1We, c1att, c1bias, h);

    // conv2
    k_lin<<<Nn / 16, TPB, 0, stream>>>(h, c2Wl, c2bl, c2Wr, c2br, xl, xr);
    k_conv<<<(Nn * 64 + TPB - 1) / TPB, TPB, 0, stream>>>(xl, xr, epack, off, c2We, c2att, c2bias, h);

    // RK4: fused per-stage kernels. k1=xl, k2=xr, k3=xl, k4 consumed in-place.
    int gOde = Nn / 16;  // 3125 blocks of 128 threads
    k_ode<0><<<gOde, 128, 0, stream>>>(h, h,  oW1, ob1, oW2, ob2, xl, ksum);
    k_ode<1><<<gOde, 128, 0, stream>>>(h, xl, oW1, ob1, oW2, ob2, xr, ksum);
    k_ode<2><<<gOde, 128, 0, stream>>>(h, xr, oW1, ob1, oW2, ob2, xl, ksum);
    k_ode<3><<<gOde, 128, 0, stream>>>(h, xl, oW1, ob1, oW2, ob2, xr, ksum);

    // pooling + head
    k_binit<<<1, Bb, 0, stream>>>(gs, ge);
    k_bounds<<<(Nn + TPB - 1) / TPB, TPB, 0, stream>>>(batch, gs, ge);
    k_pool<<<Bb, 256, 0, stream>>>(h, gs, ge, g);
    k_pred<<<(Bb * 64 + TPB - 1) / TPB, TPB, 0, stream>>>(g, pW1, pb1, pW2, pb2, out);
}

// Round 13
// 586.972 us; speedup vs baseline: 5.0118x; 1.0029x over previous
//
#include <hip/hip_runtime.h>
#include <math.h>

// Problem constants
#define Nn 50000
#define Ee 800000
#define Bb 256
#define Hh 64
#define TPB 256
#define CHUNK 512

// ---------------- embed: h = x @ W(4x64) + b ----------------
__global__ void k_embed(const float* __restrict__ x, const float* __restrict__ W,
                        const float* __restrict__ b, float* __restrict__ h) {
    int idx = blockIdx.x * blockDim.x + threadIdx.x;
    if (idx >= Nn * Hh) return;
    int n = idx >> 6, j = idx & 63;
    float acc = b[j];
#pragma unroll
    for (int d = 0; d < 4; ++d) acc += x[n * 4 + d] * W[d * Hh + j];
    h[idx] = acc;
}

// ---------------- CSR build ----------------
__global__ void k_hist(const int* __restrict__ dst, int* __restrict__ counts) {
    int e = blockIdx.x * blockDim.x + threadIdx.x;
    if (e < Ee) atomicAdd(&counts[dst[e]], 1);
}

__global__ void k_scan1(const int* __restrict__ counts, int* __restrict__ off,
                        int* __restrict__ chunksum) {
    __shared__ int s[CHUNK];
    int t = threadIdx.x;
    int base = blockIdx.x * CHUNK;
    int v = (base + t < Nn) ? counts[base + t] : 0;
    s[t] = v;
    __syncthreads();
    for (int d = 1; d < CHUNK; d <<= 1) {
        int u = (t >= d) ? s[t - d] : 0;
        __syncthreads();
        s[t] += u;
        __syncthreads();
    }
    if (base + t < Nn) off[base + t + 1] = s[t];
    if (t == CHUNK - 1) chunksum[blockIdx.x] = s[t];
}

__global__ void k_scan2(int* __restrict__ chunksum, int nch) {
    if (blockIdx.x == 0 && threadIdx.x == 0) {
        int run = 0;
        for (int i = 0; i < nch; ++i) { int v = chunksum[i]; chunksum[i] = run; run += v; }
    }
}

// scan3 + cursor init fused
__global__ void k_scan3(int* __restrict__ off, const int* __restrict__ chunkoff,
                        int* __restrict__ cursor) {
    int i = blockIdx.x * blockDim.x + threadIdx.x;
    if (i > Nn) return;
    int v;
    if (i == 0) { off[0] = 0; v = 0; }
    else {
        v = off[i] + chunkoff[(i - 1) >> 9];  // CHUNK=512
        off[i] = v;
    }
    if (i < Nn) cursor[i] = v;
}

// scatter: single 8B packed random write per edge (halves write-line traffic)
__global__ void k_scatter(const int* __restrict__ src, const int* __restrict__ dst,
                          const float* __restrict__ ea, int* __restrict__ cursor,
                          int2* __restrict__ epack) {
    int e = blockIdx.x * blockDim.x + threadIdx.x;
    if (e >= Ee) return;
    int d = dst[e];
    int p = atomicAdd(&cursor[d], 1);
    epack[p] = make_int2(src[e], __float_as_int(ea[e]));
}

// ---------------- conv linear: lane = output col (coalesced weights), 4 nodes/thread ----
__global__ __launch_bounds__(256) void k_lin(const float* __restrict__ h,
                      const float* __restrict__ Wl, const float* __restrict__ bl,
                      const float* __restrict__ Wr, const float* __restrict__ br,
                      float* __restrict__ xl, float* __restrict__ xr) {
    int lane = threadIdx.x & 63, w = threadIdx.x >> 6;
    int n0 = blockIdx.x * 16 + w * 4;      // 4 nodes per wave, 16 per block
    float al[4], ar[4];
#pragma unroll
    for (int q = 0; q < 4; ++q) { al[q] = bl[lane]; ar[q] = br[lane]; }
    for (int i4 = 0; i4 < 16; ++i4) {
        float4 hv[4];
#pragma unroll
        for (int q = 0; q < 4; ++q)
            hv[q] = *(const float4*)(h + (n0 + q) * 64 + i4 * 4);   // wave-uniform broadcast
#pragma unroll
        for (int u = 0; u < 4; ++u) {
            int i = i4 * 4 + u;
            float wlv = Wl[i * 64 + lane];   // coalesced across lanes
            float wrv = Wr[i * 64 + lane];
#pragma unroll
            for (int q = 0; q < 4; ++q) {
                float hq = ((const float*)&hv[q])[u];
                al[q] += hq * wlv;
                ar[q] += hq * wrv;
            }
        }
    }
#pragma unroll
    for (int q = 0; q < 4; ++q) {
        xl[(n0 + q) * 64 + lane] = al[q];
        xr[(n0 + q) * 64 + lane] = ar[q];
    }
}

// ---------------- fused GATv2 conv, 16-lane-group float4 layout ----------------
__global__ void k_conv(const float* __restrict__ xl, const float* __restrict__ xr,
                       const int2* __restrict__ epack, const int* __restrict__ off,
                       const float* __restrict__ We, const float* __restrict__ att,
                       const float* __restrict__ bias, float* __restrict__ hout) {
    int gid = blockIdx.x * blockDim.x + threadIdx.x;
    int n = gid >> 6, lane = gid & 63;
    if (n >= Nn) return;
    int g = lane >> 4, l16 = lane & 15;
    int s = off[n], t = off[n + 1];
    float4 xr4 = *(const float4*)(xr + (size_t)n * 64 + l16 * 4);
    float4 We4 = *(const float4*)(We + l16 * 4);
    float4 at4 = *(const float4*)(att + l16 * 4);
    float4 acc = make_float4(0.f, 0.f, 0.f, 0.f);
    float m_run = -1e30f, s_run = 0.f;
    for (int c = s; c < t; c += 4) {
        int e = c + g;
        bool valid = e < t;
        int2 pk = valid ? epack[e] : epack[c];
        int sr = pk.x;
        float ceav = valid ? __int_as_float(pk.y) : 0.f;
        float4 row = *(const float4*)(xl + (size_t)sr * 64 + l16 * 4);
        // score partial: leakyrelu(row + xr + ceav*We) . att
        float mx_ = row.x + xr4.x + ceav * We4.x;
        float my_ = row.y + xr4.y + ceav * We4.y;
        float mz_ = row.z + xr4.z + ceav * We4.z;
        float mw_ = row.w + xr4.w + ceav * We4.w;
        mx_ = mx_ > 0.f ? mx_ : 0.2f * mx_;
        my_ = my_ > 0.f ? my_ : 0.2f * my_;
        mz_ = mz_ > 0.f ? mz_ : 0.2f * mz_;
        mw_ = mw_ > 0.f ? mw_ : 0.2f * mw_;
        float pv = mx_ * at4.x + my_ * at4.y + mz_ * at4.z + mw_ * at4.w;
        // intra-group reduce (16 lanes)
#pragma unroll
        for (int o = 1; o < 16; o <<= 1) pv += __shfl_xor(pv, o);
        float ee = valid ? pv : -1e30f;
        // chunk max across groups
        float cm = ee;
        cm = fmaxf(cm, __shfl_xor(cm, 16));
        cm = fmaxf(cm, __shfl_xor(cm, 32));
        float m_new = fmaxf(m_run, cm);
        float f = __expf(m_run - m_new);
        acc.x *= f; acc.y *= f; acc.z *= f; acc.w *= f; s_run *= f;
        float w = __expf(ee - m_new);     // 0 for invalid lanes
        acc.x += w * row.x; acc.y += w * row.y;
        acc.z += w * row.z; acc.w += w * row.w;
        s_run += w;
        m_run = m_new;
    }
    // cross-group combine (groups at lane^16, lane^32)
#pragma unroll
    for (int o = 16; o <= 32; o <<= 1) {
        acc.x += __shfl_xor(acc.x, o); acc.y += __shfl_xor(acc.y, o);
        acc.z += __shfl_xor(acc.z, o); acc.w += __shfl_xor(acc.w, o);
        s_run += __shfl_xor(s_run, o);
    }
    float4 b4 = *(const float4*)(bias + l16 * 4);
    float inv = (t > s) ? 1.f / s_run : 0.f;
    float4 o4;
    o4.x = acc.x * inv + b4.x; o4.y = acc.y * inv + b4.y;
    o4.z = acc.z * inv + b4.z; o4.w = acc.w * inv + b4.w;
    o4.x = o4.x / (1.f + __expf(-o4.x));
    o4.y = o4.y / (1.f + __expf(-o4.y));
    o4.z = o4.z / (1.f + __expf(-o4.z));
    o4.w = o4.w / (1.f + __expf(-o4.w));
    if (lane < 16) *(float4*)(hout + (size_t)n * 64 + l16 * 4) = o4;
}

// ---------------- fused RK4: all 4 stages in one kernel ----------------
// block = 128 threads = 16 nodes. h0/ksum live in registers (phase-2 layout:
// thread (j=t&63, wg=t>>6) owns nodes wg*8+q, column j). y-tile and z-tile in LDS.
// Per stage: phase1 z=tanh(y@W1+b1) (thread k, 16 nodes) -> barrier ->
// phase2 kst=z@W2+b2; ksum+=w*kst; y_next=h0+cf*kst -> barrier.
__global__ __launch_bounds__(128) void k_ode4(float* __restrict__ h,
        const float* __restrict__ W1, const float* __restrict__ b1,
        const float* __restrict__ W2, const float* __restrict__ b2) {
    __shared__ float yt[16][64];
    __shared__ float zt[16][128];
    int t = threadIdx.x;
    int nb = blockIdx.x * 16;
    int j = t & 63, wg = t >> 6;
    // stage y0 = h into LDS (cooperative, coalesced)
#pragma unroll
    for (int r = 0; r < 2; ++r) {
        int f = t + r * 128;
        int nn = f >> 4, jj = (f & 15) * 4;
        *(float4*)&yt[nn][jj] = *(const float4*)(h + (size_t)(nb + nn) * 64 + jj);
    }
    // h0 + ksum registers (phase-2 layout)
    float h0[8], ksum[8];
#pragma unroll
    for (int q = 0; q < 8; ++q) {
        h0[q] = h[(size_t)(nb + wg * 8 + q) * 64 + j];
        ksum[q] = 0.f;
    }
    __syncthreads();
#pragma unroll
    for (int s = 0; s < 4; ++s) {
        const float wgt = (s == 1 || s == 2) ? 2.f : 1.f;
        const float cf = (s == 2) ? 1.f : 0.5f;   // coefficient for next stage's y
        {   // phase 1: k = t (0..127), 16 nodes per thread
            int k = t;
            float acc1[16];
#pragma unroll
            for (int q = 0; q < 16; ++q) acc1[q] = b1[k];
            for (int i4 = 0; i4 < 16; ++i4) {
                float wv4[4];
#pragma unroll
                for (int u = 0; u < 4; ++u) wv4[u] = W1[(i4 * 4 + u) * 128 + k];
#pragma unroll
                for (int half = 0; half < 2; ++half) {
                    float4 yv[8];
#pragma unroll
                    for (int q8 = 0; q8 < 8; ++q8)
                        yv[q8] = *(const float4*)&yt[half * 8 + q8][i4 * 4];
#pragma unroll
                    for (int u = 0; u < 4; ++u)
#pragma unroll
                        for (int q8 = 0; q8 < 8; ++q8)
                            acc1[half * 8 + q8] += ((const float*)&yv[q8])[u] * wv4[u];
                }
            }
#pragma unroll
            for (int q = 0; q < 16; ++q) zt[q][k] = tanhf(acc1[q]);
        }
        __syncthreads();
        {   // phase 2: (j, wg): 8 nodes per thread
            float acc2[8];
#pragma unroll
            for (int q = 0; q < 8; ++q) acc2[q] = b2[j];
            for (int k4 = 0; k4 < 32; ++k4) {
                float wv2[4];
#pragma unroll
                for (int u = 0; u < 4; ++u) wv2[u] = W2[(k4 * 4 + u) * 64 + j];
                float4 zv[8];
#pragma unroll
                for (int q = 0; q < 8; ++q)
                    zv[q] = *(const float4*)&zt[wg * 8 + q][k4 * 4];
#pragma unroll
                for (int u = 0; u < 4; ++u)
#pragma unroll
                    for (int q = 0; q < 8; ++q)
                        acc2[q] += ((const float*)&zv[q])[u] * wv2[u];
            }
#pragma unroll
            for (int q = 0; q < 8; ++q) {
                ksum[q] += wgt * acc2[q];
                if (s < 3) yt[wg * 8 + q][j] = h0[q] + cf * acc2[q];
            }
        }
        __syncthreads();
    }
    // epilogue: h = h0 + ksum/6
#pragma unroll
    for (int q = 0; q < 8; ++q)
        h[(size_t)(nb + wg * 8 + q) * 64 + j] = h0[q] + ksum[q] * (1.f / 6.f);
}

// ---------------- pooling ----------------
__global__ void k_binit(int* __restrict__ gs, int* __restrict__ ge) {
    int b = threadIdx.x;
    if (b < Bb) { gs[b] = 0; ge[b] = 0; }
}

__global__ void k_bounds(const int* __restrict__ batch, int* __restrict__ gs,
                         int* __restrict__ ge) {
    int n = blockIdx.x * blockDim.x + threadIdx.x;
    if (n >= Nn) return;
    int b = batch[n];
    if (n == 0 || batch[n - 1] != b) gs[b] = n;
    if (n == Nn - 1 || batch[n + 1] != b) ge[b] = n + 1;
}

__global__ void k_pool(const float* __restrict__ h, const int* __restrict__ gs,
                       const int* __restrict__ ge, float* __restrict__ g) {
    int b = blockIdx.x;
    int s = gs[b], e = ge[b];
    int w = threadIdx.x >> 6, lane = threadIdx.x & 63;
    float sum = 0.f, mx = -1e30f;
    for (int n = s + w; n < e; n += 4) {
        float v = h[n * Hh + lane];
        sum += v;
        mx = fmaxf(mx, v);
    }
    __shared__ float ssum[4][64], smx[4][64];
    ssum[w][lane] = sum;
    smx[w][lane] = mx;
    __syncthreads();
    if (threadIdx.x < 64) {
        int j = threadIdx.x;
        float su = ssum[0][j] + ssum[1][j] + ssum[2][j] + ssum[3][j];
        float m2 = fmaxf(fmaxf(smx[0][j], smx[1][j]), fmaxf(smx[2][j], smx[3][j]));
        int cnt = e - s;
        g[b * 2 * Hh + j] = (cnt > 0) ? su / (float)cnt : 0.f;
        g[b * 2 * Hh + Hh + j] = (cnt > 0) ? m2 : 0.f;
    }
}

// ---------------- predictor head: wave per graph ----------------
__global__ void k_pred(const float* __restrict__ g, const float* __restrict__ W1,
                       const float* __restrict__ b1, const float* __restrict__ W2,
                       const float* __restrict__ b2, float* __restrict__ out) {
    int gid = blockIdx.x * blockDim.x + threadIdx.x;
    int b = gid >> 6, lane = gid & 63;
    if (b >= Bb) return;
    int hh = lane & 31, half = lane >> 5;
    const float* gr = g + b * 2 * Hh + half * Hh;
    float a = 0.f;
#pragma unroll 8
    for (int i = 0; i < Hh; ++i) a += gr[i] * W1[(half * Hh + i) * 32 + hh];
    a += __shfl_xor(a, 32);
    a += b1[hh];
    float sl = a / (1.f + expf(-a));
    float partial = (half == 0) ? sl * W2[hh] : 0.f;
#pragma unroll
    for (int o = 32; o > 0; o >>= 1) partial += __shfl_xor(partial, o);
    if (lane == 0) out[b] = partial + b2[0];
}

extern "C" void kernel_launch(void* const* d_in, const int* in_sizes, int n_in,
                              void* d_out, int out_size, void* d_ws, size_t ws_size,
                              hipStream_t stream) {
    const float* x     = (const float*)d_in[0];
    const int*   ei    = (const int*)d_in[1];
    const float* ea    = (const float*)d_in[2];
    const int*   batch = (const int*)d_in[3];
    const float* embW  = (const float*)d_in[4];
    const float* embB  = (const float*)d_in[5];
    const float* c1Wl = (const float*)d_in[6];  const float* c1bl = (const float*)d_in[7];
    const float* c1Wr = (const float*)d_in[8];  const float* c1br = (const float*)d_in[9];
    const float* c1We = (const float*)d_in[10]; const float* c1att = (const float*)d_in[11];
    const float* c1bias = (const float*)d_in[12];
    const float* c2Wl = (const float*)d_in[13]; const float* c2bl = (const float*)d_in[14];
    const float* c2Wr = (const float*)d_in[15]; const float* c2br = (const float*)d_in[16];
    const float* c2We = (const float*)d_in[17]; const float* c2att = (const float*)d_in[18];
    const float* c2bias = (const float*)d_in[19];
    const float* oW1 = (const float*)d_in[20]; const float* ob1 = (const float*)d_in[21];
    const float* oW2 = (const float*)d_in[22]; const float* ob2 = (const float*)d_in[23];
    const float* pW1 = (const float*)d_in[24]; const float* pb1 = (const float*)d_in[25];
    const float* pW2 = (const float*)d_in[26]; const float* pb2 = (const float*)d_in[27];
    float* out = (float*)d_out;

    // workspace layout (floats)
    float* fws = (float*)d_ws;
    size_t NH = (size_t)Nn * Hh;           // 3.2M
    float* h    = fws;
    float* xl   = fws + NH;
    float* xr   = fws + 2 * NH;
    int2*  epack = (int2*)(fws + 3 * NH);  // [Ee] packed (src, ea)
    float* g    = (float*)(epack + Ee);    // [Bb*128]
    int* iws = (int*)(g + (size_t)Bb * 128);
    int* counts = iws;                     // [Nn]
    int* off    = counts + Nn;             // [Nn+1]
    int* cursor = off + Nn + 1;            // [Nn]
    int* chk    = cursor + Nn;             // [128]
    int* gs     = chk + 128;               // [Bb]
    int* ge     = gs + Bb;                 // [Bb]

    const int* src = ei;
    const int* dst = ei + Ee;

    hipMemsetAsync(counts, 0, Nn * sizeof(int), stream);
    k_embed<<<(Nn * Hh + TPB - 1) / TPB, TPB, 0, stream>>>(x, embW, embB, h);
    k_hist<<<(Ee + TPB - 1) / TPB, TPB, 0, stream>>>(dst, counts);
    k_scan1<<<(Nn + CHUNK - 1) / CHUNK, CHUNK, 0, stream>>>(counts, off, chk);
    k_scan2<<<1, 64, 0, stream>>>(chk, (Nn + CHUNK - 1) / CHUNK);
    k_scan3<<<(Nn + 1 + TPB - 1) / TPB, TPB, 0, stream>>>(off, chk, cursor);
    k_scatter<<<(Ee + TPB - 1) / TPB, TPB, 0, stream>>>(src, dst, ea, cursor, epack);

    // conv1
    k_lin<<<Nn / 16, TPB, 0, stream>>>(h, c1Wl, c1bl, c1Wr, c1br, xl, xr);
    k_conv<<<(Nn * 64 + TPB - 1) / TPB, TPB, 0, stream>>>(xl, xr, epack, off, c1We, c1att, c1bias, h);

    // conv2
    k_lin<<<Nn / 16, TPB, 0, stream>>>(h, c2Wl, c2bl, c2Wr, c2br, xl, xr);
    k_conv<<<(Nn * 64 + TPB - 1) / TPB, TPB, 0, stream>>>(xl, xr, epack, off, c2We, c2att, c2bias, h);

    // fused RK4 (all 4 stages, per-node independent)
    k_ode4<<<Nn / 16, 128, 0, stream>>>(h, oW1, ob1, oW2, ob2);

    // pooling + head
    k_binit<<<1, Bb, 0, stream>>>(gs, ge);
    k_bounds<<<(Nn + TPB - 1) / TPB, TPB, 0, stream>>>(batch, gs, ge);
    k_pool<<<Bb, 256, 0, stream>>>(h, gs, ge, g);
    k_pred<<<(Bb * 64 + TPB - 1) / TPB, TPB, 0, stream>>>(g, pW1, pb1, pW2, pb2, out);
}